// Round 6
// baseline (483.473 us; speedup 1.0000x reference)
//
#include <hip/hip_runtime.h>

#define NN 100000
#define EE 1600000
#define EPE 500000
#define NBINS 196        // ceil(NN/512), bin = dst >> 9
#define BCAP 12288       // slots per bin (avg 8192, sigma ~90 -> huge margin)
#define EPB 2048         // edges per block in binpass1
#define NB1 782          // ceil(EE/EPB)
#define NBG 391          // node blocks: ceil(NN/256)

typedef short bf8_t __attribute__((ext_vector_type(8)));   // 8 x bf16 (4 VGPRs)
typedef float f4_t  __attribute__((ext_vector_type(4)));   // MFMA accumulator

__device__ __forceinline__ unsigned short f2bf(float f) {
    unsigned u = __float_as_uint(f);
    unsigned r = (u + 0x7fffu + ((u >> 16) & 1u)) >> 16;   // RNE
    return (unsigned short)r;
}
__device__ __forceinline__ float bfl(unsigned u) { return __uint_as_float(u << 16); }
__device__ __forceinline__ float bfh(unsigned u) { return __uint_as_float(u & 0xffff0000u); }

// layer0 storage perm: mem offset m (0..127) -> true col
__device__ __host__ __forceinline__ int c0p(int m) {
    return ((m & 7) << 4) | (((m >> 4) & 7) << 1) | ((m >> 3) & 1);
}
// layer1 storage perm: mem offset m (0..63) -> true col
__device__ __host__ __forceinline__ int c1p(int m) {
    return ((m & 3) << 4) | (((m >> 4) & 3) << 2) | ((m >> 2) & 3);
}

// ---------------- binned CSR build ----------------
__global__ __launch_bounds__(256) void binpass1_k(
    const int* __restrict__ src, const int* __restrict__ dst,
    int* __restrict__ bin_cnt, int* __restrict__ binbuf)
{
    __shared__ int cnt_l[NBINS];
    __shared__ int base_l[NBINS];
    int tid = threadIdx.x;
    int e0 = blockIdx.x * EPB;
    for (int i = tid; i < NBINS; i += 256) cnt_l[i] = 0;
    __syncthreads();

    int pk[8];
    #pragma unroll
    for (int i = 0; i < 8; ++i) {
        int e = e0 + tid + i * 256;
        pk[i] = -1;
        if (e < EE) {
            int d = dst[e];
            int b = d >> 9;
            int r = atomicAdd(&cnt_l[b], 1);        // r < 2048
            pk[i] = (b << 20) | ((d & 511) << 11) | r;
        }
    }
    __syncthreads();
    for (int i = tid; i < NBINS; i += 256)
        base_l[i] = atomicAdd(&bin_cnt[i], cnt_l[i]);
    __syncthreads();

    #pragma unroll
    for (int i = 0; i < 8; ++i) {
        int e = e0 + tid + i * 256;
        if (e >= EE) continue;
        int v = pk[i];
        int b = v >> 20, dl = (v >> 11) & 511, r = v & 2047;
        binbuf[b * BCAP + base_l[b] + r] = (dl << 17) | src[e];  // src<2^17
    }
}

__global__ __launch_bounds__(256) void binpass2_k(
    const int* __restrict__ binbuf, const int* __restrict__ bin_cnt,
    int* __restrict__ csr, int* __restrict__ row_ptr, float* __restrict__ invd)
{
    __shared__ int deg_l[512];
    __shared__ int off_l[512];
    __shared__ int cur_l[512];
    __shared__ int s[256];
    int tid = threadIdx.x;
    int b = blockIdx.x;
    int lo = b << 9;
    int n_here = min(512, NN - lo);

    int bc = (tid < NBINS) ? bin_cnt[tid] : 0;
    s[tid] = bc;
    __syncthreads();
    #pragma unroll
    for (int off = 1; off < 256; off <<= 1) {
        int t = (tid >= off) ? s[tid - off] : 0;
        __syncthreads();
        s[tid] += t;
        __syncthreads();
    }
    int base = (b == 0) ? 0 : s[b - 1];
    int cnt = bin_cnt[b];
    const int* bb = binbuf + b * BCAP;
    __syncthreads();

    deg_l[tid] = 0; deg_l[tid + 256] = 0;
    __syncthreads();
    for (int i = tid; i < cnt; i += 256)
        atomicAdd(&deg_l[bb[i] >> 17], 1);
    __syncthreads();

    int a0 = deg_l[2 * tid], a1 = deg_l[2 * tid + 1];
    s[tid] = a0 + a1;
    __syncthreads();
    #pragma unroll
    for (int off = 1; off < 256; off <<= 1) {
        int t = (tid >= off) ? s[tid - off] : 0;
        __syncthreads();
        s[tid] += t;
        __syncthreads();
    }
    int excl = s[tid] - (a0 + a1);
    off_l[2 * tid] = excl;
    off_l[2 * tid + 1] = excl + a0;
    cur_l[2 * tid] = excl;
    cur_l[2 * tid + 1] = excl + a0;
    __syncthreads();

    for (int j = tid; j < n_here; j += 256) {
        row_ptr[lo + j] = base + off_l[j];
        invd[lo + j] = 1.0f / fmaxf((float)deg_l[j], 1.0f);
    }
    if (tid == 0 && b == NBINS - 1) row_ptr[NN] = EE;

    for (int i = tid; i < cnt; i += 256) {
        int v = bb[i];
        int dstl = v >> 17, srcv = v & 0x1FFFF;
        int pos = atomicAdd(&cur_l[dstl], 1);
        csr[base + pos] = srcv;
    }
}

// ---------------- combined weight/bias pack ----------------
// Bp0: identity (x is natural order). Bp1: rows = h1 mem offsets -> true col c0p.
// b0p[m] = bl0[c0p(m)], b1p[m] = bl1[c1p(m)].
__global__ void pack_k(const float* __restrict__ Wl0, const float* __restrict__ Wr0,
                       const float* __restrict__ Wl1, const float* __restrict__ Wr1,
                       const float* __restrict__ bl0, const float* __restrict__ bl1,
                       unsigned short* __restrict__ Bp0, unsigned short* __restrict__ Bp1,
                       float* __restrict__ b0p, float* __restrict__ b1p)
{
    int t = blockIdx.x * 256 + threadIdx.x;
    if (t < 4096) {                     // Bp0: (kt, n, q), ntot=256, ncl=128
        int q = t & 3;
        int n = (t >> 2) & 255;
        int kt = t >> 10;
        unsigned short o[8];
        #pragma unroll
        for (int j = 0; j < 8; ++j) {
            int k = kt * 32 + q * 8 + j;
            float v = (n < 128) ? Wl0[(size_t)k * 128 + n] : Wr0[(size_t)k * 128 + (n - 128)];
            o[j] = f2bf(v);
        }
        uint4 w;
        w.x = (unsigned)o[0] | ((unsigned)o[1] << 16);
        w.y = (unsigned)o[2] | ((unsigned)o[3] << 16);
        w.z = (unsigned)o[4] | ((unsigned)o[5] << 16);
        w.w = (unsigned)o[6] | ((unsigned)o[7] << 16);
        *(uint4*)(Bp0 + (size_t)t * 8) = w;
    } else if (t < 6144) {              // Bp1: ntot=128, ncl=64, h1-perm rows
        int u = t - 4096;
        int q = u & 3;
        int n = (u >> 2) & 127;
        int kt = u >> 9;
        unsigned short o[8];
        #pragma unroll
        for (int j = 0; j < 8; ++j) {
            int k = kt * 32 + q * 8 + j;          // h1 mem offset
            int c = c0p(k);                       // true column
            float v = (n < 64) ? Wl1[(size_t)c * 64 + n] : Wr1[(size_t)c * 64 + (n - 64)];
            o[j] = f2bf(v);
        }
        uint4 w;
        w.x = (unsigned)o[0] | ((unsigned)o[1] << 16);
        w.y = (unsigned)o[2] | ((unsigned)o[3] << 16);
        w.z = (unsigned)o[4] | ((unsigned)o[5] << 16);
        w.w = (unsigned)o[6] | ((unsigned)o[7] << 16);
        *(uint4*)(Bp1 + (size_t)u * 8) = w;
    } else if (t < 6144 + 128) {
        int m = t - 6144;
        b0p[m] = bl0[c0p(m)];
    } else if (t < 6144 + 192) {
        int m = t - 6272;
        b1p[m] = bl1[c1p(m)];
    }
}

// ---------------- MFMA GEMM: [t | r] = A @ [Wl | Wr], K=128 ----------------
// Outputs stored GROUP-MAJOR: NG = NCOLS/32 groups per half, each [NN][16] ushorts.
// NTH=8: group=ln>>1, slot=(ln&1)*8+nt. NTH=4: group=ln>>2, slot=(ln&3)*4+nt.
// AFP32: A = x (natural fp32). else: A = h1 group-major (8 groups).
template<int NCOLS, bool AFP32>
__global__ __launch_bounds__(256) void gemm_k(
    const void* __restrict__ Av, const unsigned short* __restrict__ Bp,
    unsigned short* __restrict__ Tout, unsigned short* __restrict__ Rout)
{
    constexpr int NT = NCOLS / 16;
    constexpr int NTH = NCOLS / 32;
    int wave = threadIdx.x >> 6;
    int lane = threadIdx.x & 63;
    int ln = lane & 15, q = lane >> 4;
    int row0 = (blockIdx.x * 4 + wave) * 16;
    if (row0 >= NN) return;
    int arow = row0 + ln;

    f4_t acc[NT];
    #pragma unroll
    for (int nt = 0; nt < NT; ++nt) acc[nt] = (f4_t){0.f, 0.f, 0.f, 0.f};

    #pragma unroll
    for (int kt = 0; kt < 4; ++kt) {
        bf8_t a;
        if (AFP32) {
            const float* ap = (const float*)Av + (size_t)arow * 128 + kt * 32 + q * 8;
            f4_t a0 = *(const f4_t*)ap;
            f4_t a1 = *(const f4_t*)(ap + 4);
            #pragma unroll
            for (int j = 0; j < 4; ++j) {
                a[j]     = (short)f2bf(a0[j]);
                a[4 + j] = (short)f2bf(a1[j]);
            }
        } else {
            int g = kt * 2 + (q >> 1);
            int slot = (q & 1) * 8;
            a = *(const bf8_t*)((const unsigned short*)Av + ((size_t)g * NN + arow) * 16 + slot);
        }
        const unsigned short* bb = Bp + (size_t)kt * NCOLS * 32 + (size_t)ln * 32 + q * 8;
        #pragma unroll
        for (int nt = 0; nt < NT; ++nt) {
            bf8_t b = *(const bf8_t*)(bb + nt * 512);
            acc[nt] = __builtin_amdgcn_mfma_f32_16x16x32_bf16(a, b, acc[nt], 0, 0, 0);
        }
    }

    #pragma unroll
    for (int r = 0; r < 4; ++r) {
        int row = row0 + q * 4 + r;
        if (NTH == 8) {
            size_t tb = ((size_t)(ln >> 1) * NN + row) * 16 + (ln & 1) * 8;
            uint4 wt, wr;
            wt.x = (unsigned)f2bf(acc[0][r]) | ((unsigned)f2bf(acc[1][r]) << 16);
            wt.y = (unsigned)f2bf(acc[2][r]) | ((unsigned)f2bf(acc[3][r]) << 16);
            wt.z = (unsigned)f2bf(acc[4][r]) | ((unsigned)f2bf(acc[5][r]) << 16);
            wt.w = (unsigned)f2bf(acc[6][r]) | ((unsigned)f2bf(acc[7][r]) << 16);
            wr.x = (unsigned)f2bf(acc[8][r])  | ((unsigned)f2bf(acc[9][r])  << 16);
            wr.y = (unsigned)f2bf(acc[10][r]) | ((unsigned)f2bf(acc[11][r]) << 16);
            wr.z = (unsigned)f2bf(acc[12][r]) | ((unsigned)f2bf(acc[13][r]) << 16);
            wr.w = (unsigned)f2bf(acc[14][r]) | ((unsigned)f2bf(acc[15][r]) << 16);
            *(uint4*)(Tout + tb) = wt;
            *(uint4*)(Rout + tb) = wr;
        } else {
            size_t tb = ((size_t)(ln >> 2) * NN + row) * 16 + (ln & 3) * 4;
            uint2 wt, wr;
            wt.x = (unsigned)f2bf(acc[0][r]) | ((unsigned)f2bf(acc[1][r]) << 16);
            wt.y = (unsigned)f2bf(acc[2][r]) | ((unsigned)f2bf(acc[3][r]) << 16);
            wr.x = (unsigned)f2bf(acc[4][r]) | ((unsigned)f2bf(acc[5][r]) << 16);
            wr.y = (unsigned)f2bf(acc[6][r]) | ((unsigned)f2bf(acc[7][r]) << 16);
            *(uint2*)(Tout + tb) = wt;
            *(uint2*)(Rout + tb) = wr;
        }
    }
}

// ---------------- fused gather-mean + combine, group-strip version ----------------
// One lane per (node, group). Group g pinned to XCD via blockIdx % NGROUPS.
// Random reads confined to tg group plane (3.2 MB, L2-resident per XCD).
__device__ __forceinline__ void acc8(float* a, uint4 v) {
    a[0] += bfl(v.x); a[1] += bfh(v.x);
    a[2] += bfl(v.y); a[3] += bfh(v.y);
    a[4] += bfl(v.z); a[5] += bfh(v.z);
    a[6] += bfl(v.w); a[7] += bfh(v.w);
}
__device__ __forceinline__ void unp8(float* a, uint4 v) {
    a[0] = bfl(v.x); a[1] = bfh(v.x);
    a[2] = bfl(v.y); a[3] = bfh(v.y);
    a[4] = bfl(v.z); a[5] = bfh(v.z);
    a[6] = bfl(v.w); a[7] = bfh(v.w);
}

template<int NGROUPS, bool RELU>
__global__ __launch_bounds__(256) void gather_fuse_k(
    const unsigned short* __restrict__ tg, const int* __restrict__ csr,
    const int* __restrict__ row_ptr, const float* __restrict__ invd,
    const unsigned short* __restrict__ rg, const float* __restrict__ biasp,
    unsigned short* __restrict__ outg)
{
    int g = blockIdx.x % NGROUPS;
    int node = (blockIdx.x / NGROUPS) * 256 + threadIdx.x;
    if (node >= NN) return;
    const unsigned short* base = tg + (size_t)g * NN * 16;
    int e = row_ptr[node];
    int e1 = row_ptr[node + 1];

    float a0[16], a1[16];
    #pragma unroll
    for (int j = 0; j < 16; ++j) { a0[j] = 0.f; a1[j] = 0.f; }

    for (; e + 1 < e1; e += 2) {
        int s0 = csr[e], s1 = csr[e + 1];
        const unsigned short* p0 = base + (size_t)s0 * 16;
        const unsigned short* p1 = base + (size_t)s1 * 16;
        uint4 v00 = *(const uint4*)p0;
        uint4 v01 = *(const uint4*)(p0 + 8);
        uint4 v10 = *(const uint4*)p1;
        uint4 v11 = *(const uint4*)(p1 + 8);
        acc8(a0, v00); acc8(a0 + 8, v01);
        acc8(a1, v10); acc8(a1 + 8, v11);
    }
    if (e < e1) {
        int s0 = csr[e];
        const unsigned short* p0 = base + (size_t)s0 * 16;
        uint4 v00 = *(const uint4*)p0;
        uint4 v01 = *(const uint4*)(p0 + 8);
        acc8(a0, v00); acc8(a0 + 8, v01);
    }

    float inv = invd[node];
    const unsigned short* rp = rg + ((size_t)g * NN + node) * 16;
    uint4 rv0 = *(const uint4*)rp;
    uint4 rv1 = *(const uint4*)(rp + 8);
    float rr[16];
    unp8(rr, rv0); unp8(rr + 8, rv1);
    const float* bp = biasp + g * 16;

    unsigned short o[16];
    #pragma unroll
    for (int j = 0; j < 16; ++j) {
        float v = (a0[j] + a1[j]) * inv + rr[j] + bp[j];
        o[j] = f2bf(RELU ? fmaxf(v, 0.f) : v);
    }
    uint4 w0, w1;
    w0.x = (unsigned)o[0]  | ((unsigned)o[1]  << 16);
    w0.y = (unsigned)o[2]  | ((unsigned)o[3]  << 16);
    w0.z = (unsigned)o[4]  | ((unsigned)o[5]  << 16);
    w0.w = (unsigned)o[6]  | ((unsigned)o[7]  << 16);
    w1.x = (unsigned)o[8]  | ((unsigned)o[9]  << 16);
    w1.y = (unsigned)o[10] | ((unsigned)o[11] << 16);
    w1.z = (unsigned)o[12] | ((unsigned)o[13] << 16);
    w1.w = (unsigned)o[14] | ((unsigned)o[15] << 16);
    unsigned short* op = outg + ((size_t)g * NN + node) * 16;
    *(uint4*)op = w0;
    *(uint4*)(op + 8) = w1;
}

// ---------------- edge scoring: 4 quarter passes, 1 lane per (edge, quarter) ----------------
__device__ __forceinline__ float dot8(uint4 va, uint4 vb) {
    return bfl(va.x) * bfl(vb.x) + bfh(va.x) * bfh(vb.x)
         + bfl(va.y) * bfl(vb.y) + bfh(va.y) * bfh(vb.y)
         + bfl(va.z) * bfl(vb.z) + bfh(va.z) * bfh(vb.z)
         + bfl(va.w) * bfl(vb.w) + bfh(va.w) * bfh(vb.w);
}

__global__ __launch_bounds__(256) void score_k(
    const unsigned short* __restrict__ h2q, const int* __restrict__ pos,
    const int* __restrict__ neg, float* __restrict__ out)
{
    int qd = blockIdx.x & 3;
    int eg = (blockIdx.x >> 2) * 256 + threadIdx.x;
    if (eg >= 2 * EPE) return;
    int a, b;
    if (eg < EPE) { a = pos[eg]; b = pos[EPE + eg]; }
    else { int e2 = eg - EPE; a = neg[e2]; b = neg[EPE + e2]; }
    const unsigned short* hb = h2q + (size_t)qd * NN * 16;
    const unsigned short* pa = hb + (size_t)a * 16;
    const unsigned short* pb = hb + (size_t)b * 16;
    uint4 va0 = *(const uint4*)pa;
    uint4 va1 = *(const uint4*)(pa + 8);
    uint4 vb0 = *(const uint4*)pb;
    uint4 vb1 = *(const uint4*)(pb + 8);
    float p = dot8(va0, vb0) + dot8(va1, vb1);
    atomicAdd(&out[eg], p);
}

extern "C" void kernel_launch(void* const* d_in, const int* in_sizes, int n_in,
                              void* d_out, int out_size, void* d_ws, size_t ws_size,
                              hipStream_t stream) {
    const float* x   = (const float*)d_in[0];
    const int*   ei  = (const int*)d_in[1];
    const int*   pei = (const int*)d_in[2];
    const int*   nei = (const int*)d_in[3];
    const float* Wl0 = (const float*)d_in[4];
    const float* bl0 = (const float*)d_in[5];
    const float* Wr0 = (const float*)d_in[6];
    const float* Wl1 = (const float*)d_in[7];
    const float* bl1 = (const float*)d_in[8];
    const float* Wr1 = (const float*)d_in[9];
    float* out = (float*)d_out;

    char* ws = (char*)d_ws;
    size_t off = 0;
    auto alloc = [&](size_t bytes) {
        void* p = ws + off;
        off = (off + bytes + 255) & ~(size_t)255;
        return p;
    };
    float* invd     = (float*)alloc((size_t)NN * 4);
    int*   row_ptr  = (int*)  alloc((size_t)(NN + 1) * 4);
    int*   bin_cnt  = (int*)  alloc((size_t)NBINS * 4);
    int*   binbuf   = (int*)  alloc((size_t)NBINS * BCAP * 4);
    int*   csr      = (int*)  alloc((size_t)EE * 4);
    unsigned short* Bp0 = (unsigned short*)alloc((size_t)4096 * 8 * 2);
    unsigned short* Bp1 = (unsigned short*)alloc((size_t)2048 * 8 * 2);
    float* b0p = (float*)alloc(128 * 4);
    float* b1p = (float*)alloc(64 * 4);
    unsigned short* t0g = (unsigned short*)alloc((size_t)8 * NN * 16 * 2);  // t1g aliases
    unsigned short* r0g = (unsigned short*)alloc((size_t)8 * NN * 16 * 2);  // r1g aliases
    unsigned short* h1g = (unsigned short*)alloc((size_t)8 * NN * 16 * 2);  // h2q aliases
    unsigned short* t1g = t0g;
    unsigned short* r1g = r0g;
    unsigned short* h2q = h1g;

    const int* src = ei;        // edge_index[0]
    const int* dst = ei + EE;   // edge_index[1]

    hipMemsetAsync(bin_cnt, 0, (size_t)NBINS * 4, stream);
    hipMemsetAsync(out, 0, (size_t)2 * EPE * 4, stream);

    // binned CSR build
    binpass1_k<<<NB1, 256, 0, stream>>>(src, dst, bin_cnt, binbuf);
    binpass2_k<<<NBINS, 256, 0, stream>>>(binbuf, bin_cnt, csr, row_ptr, invd);

    // weight + bias packing
    pack_k<<<25, 256, 0, stream>>>(Wl0, Wr0, Wl1, Wr1, bl0, bl1, Bp0, Bp1, b0p, b1p);

    // layer 0: [t0 | r0] = x @ [Wl0 | Wr0]; h1 = relu(mean(t0) + r0 + b0)
    gemm_k<256, true><<<1563, 256, 0, stream>>>(x, Bp0, t0g, r0g);
    gather_fuse_k<8, true><<<8 * NBG, 256, 0, stream>>>(
        t0g, csr, row_ptr, invd, r0g, b0p, h1g);

    // layer 1: [t1 | r1] = h1 @ [Wl1 | Wr1]; h2 = mean(t1) + r1 + b1
    gemm_k<128, false><<<1563, 256, 0, stream>>>(h1g, Bp1, t1g, r1g);
    gather_fuse_k<4, false><<<4 * NBG, 256, 0, stream>>>(
        t1g, csr, row_ptr, invd, r1g, b1p, h2q);

    // scoring: 4 XCD-pinned quarter passes, atomic accumulate
    score_k<<<4 * ((2 * EPE + 255) / 256), 256, 0, stream>>>(h2q, pei, nei, out);
}

// Round 7
// 299.034 us; speedup vs baseline: 1.6168x; 1.6168x over previous
//
#include <hip/hip_runtime.h>

#define NN 100000
#define EE 1600000
#define EPE 500000
#define NBINS 196        // ceil(NN/512), bin = dst >> 9
#define BCAP 12288       // slots per bin (avg 8192, sigma ~90 -> huge margin)
#define EPB 2048         // edges per block in binpass1
#define NB1 782          // ceil(EE/EPB)

typedef short bf8_t __attribute__((ext_vector_type(8)));   // 8 x bf16 (4 VGPRs)
typedef float f4_t  __attribute__((ext_vector_type(4)));   // MFMA accumulator
typedef float f2v  __attribute__((ext_vector_type(2)));

__device__ __forceinline__ unsigned short f2bf(float f) {
    unsigned u = __float_as_uint(f);
    unsigned r = (u + 0x7fffu + ((u >> 16) & 1u)) >> 16;   // RNE
    return (unsigned short)r;
}
__device__ __forceinline__ float bfl(unsigned u) { return __uint_as_float(u << 16); }
__device__ __forceinline__ float bfh(unsigned u) { return __uint_as_float(u & 0xffff0000u); }

// ---------------- fp8 e4m3 encode/decode ----------------
#if __has_builtin(__builtin_amdgcn_cvt_pk_fp8_f32) && __has_builtin(__builtin_amdgcn_cvt_pk_f32_fp8)
__device__ __forceinline__ unsigned pk4_fp8(float a0, float a1, float a2, float a3) {
    int w = 0;
    w = __builtin_amdgcn_cvt_pk_fp8_f32(a0, a1, w, false);
    w = __builtin_amdgcn_cvt_pk_fp8_f32(a2, a3, w, true);
    return (unsigned)w;
}
__device__ __forceinline__ void accf8(float* a, uint2 v) {
    f2v p0 = __builtin_amdgcn_cvt_pk_f32_fp8((int)v.x, false);
    f2v p1 = __builtin_amdgcn_cvt_pk_f32_fp8((int)v.x, true);
    f2v p2 = __builtin_amdgcn_cvt_pk_f32_fp8((int)v.y, false);
    f2v p3 = __builtin_amdgcn_cvt_pk_f32_fp8((int)v.y, true);
    a[0] += p0.x; a[1] += p0.y; a[2] += p1.x; a[3] += p1.y;
    a[4] += p2.x; a[5] += p2.y; a[6] += p3.x; a[7] += p3.y;
}
#else
#include <hip/hip_fp8.h>
__device__ __forceinline__ unsigned pk4_fp8(float a0, float a1, float a2, float a3) {
    unsigned r;
    r  = (unsigned)__hip_cvt_float_to_fp8(a0, __HIP_SATFINITE, __HIP_E4M3);
    r |= (unsigned)__hip_cvt_float_to_fp8(a1, __HIP_SATFINITE, __HIP_E4M3) << 8;
    r |= (unsigned)__hip_cvt_float_to_fp8(a2, __HIP_SATFINITE, __HIP_E4M3) << 16;
    r |= (unsigned)__hip_cvt_float_to_fp8(a3, __HIP_SATFINITE, __HIP_E4M3) << 24;
    return r;
}
__device__ __forceinline__ float dec1_fp8(unsigned b) {
    __hip_fp8_e4m3 h; h.__x = (__hip_fp8_storage_t)(b & 0xff);
    return (float)h;
}
__device__ __forceinline__ void accf8(float* a, uint2 v) {
    a[0] += dec1_fp8(v.x); a[1] += dec1_fp8(v.x >> 8);
    a[2] += dec1_fp8(v.x >> 16); a[3] += dec1_fp8(v.x >> 24);
    a[4] += dec1_fp8(v.y); a[5] += dec1_fp8(v.y >> 8);
    a[6] += dec1_fp8(v.y >> 16); a[7] += dec1_fp8(v.y >> 24);
}
#endif

// ---------------- binned CSR build ----------------
__global__ __launch_bounds__(256) void binpass1_k(
    const int* __restrict__ src, const int* __restrict__ dst,
    int* __restrict__ bin_cnt, int* __restrict__ binbuf)
{
    __shared__ int cnt_l[NBINS];
    __shared__ int base_l[NBINS];
    int tid = threadIdx.x;
    int e0 = blockIdx.x * EPB;
    for (int i = tid; i < NBINS; i += 256) cnt_l[i] = 0;
    __syncthreads();

    int pk[8];
    #pragma unroll
    for (int i = 0; i < 8; ++i) {
        int e = e0 + tid + i * 256;
        pk[i] = -1;
        if (e < EE) {
            int d = dst[e];
            int b = d >> 9;
            int r = atomicAdd(&cnt_l[b], 1);        // r < 2048
            pk[i] = (b << 20) | ((d & 511) << 11) | r;
        }
    }
    __syncthreads();
    for (int i = tid; i < NBINS; i += 256)
        base_l[i] = atomicAdd(&bin_cnt[i], cnt_l[i]);
    __syncthreads();

    #pragma unroll
    for (int i = 0; i < 8; ++i) {
        int e = e0 + tid + i * 256;
        if (e >= EE) continue;
        int v = pk[i];
        int b = v >> 20, dl = (v >> 11) & 511, r = v & 2047;
        binbuf[b * BCAP + base_l[b] + r] = (dl << 17) | src[e];  // src<2^17
    }
}

__global__ __launch_bounds__(256) void binpass2_k(
    const int* __restrict__ binbuf, const int* __restrict__ bin_cnt,
    int* __restrict__ csr, int* __restrict__ row_ptr, float* __restrict__ invd)
{
    __shared__ int deg_l[512];
    __shared__ int off_l[512];
    __shared__ int cur_l[512];
    __shared__ int s[256];
    int tid = threadIdx.x;
    int b = blockIdx.x;
    int lo = b << 9;
    int n_here = min(512, NN - lo);

    int bc = (tid < NBINS) ? bin_cnt[tid] : 0;
    s[tid] = bc;
    __syncthreads();
    #pragma unroll
    for (int off = 1; off < 256; off <<= 1) {
        int t = (tid >= off) ? s[tid - off] : 0;
        __syncthreads();
        s[tid] += t;
        __syncthreads();
    }
    int base = (b == 0) ? 0 : s[b - 1];
    int cnt = bin_cnt[b];
    const int* bb = binbuf + b * BCAP;
    __syncthreads();

    deg_l[tid] = 0; deg_l[tid + 256] = 0;
    __syncthreads();
    for (int i = tid; i < cnt; i += 256)
        atomicAdd(&deg_l[bb[i] >> 17], 1);
    __syncthreads();

    int a0 = deg_l[2 * tid], a1 = deg_l[2 * tid + 1];
    s[tid] = a0 + a1;
    __syncthreads();
    #pragma unroll
    for (int off = 1; off < 256; off <<= 1) {
        int t = (tid >= off) ? s[tid - off] : 0;
        __syncthreads();
        s[tid] += t;
        __syncthreads();
    }
    int excl = s[tid] - (a0 + a1);
    off_l[2 * tid] = excl;
    off_l[2 * tid + 1] = excl + a0;
    cur_l[2 * tid] = excl;
    cur_l[2 * tid + 1] = excl + a0;
    __syncthreads();

    for (int j = tid; j < n_here; j += 256) {
        row_ptr[lo + j] = base + off_l[j];
        invd[lo + j] = 1.0f / fmaxf((float)deg_l[j], 1.0f);
    }
    if (tid == 0 && b == NBINS - 1) row_ptr[NN] = EE;

    for (int i = tid; i < cnt; i += 256) {
        int v = bb[i];
        int dstl = v >> 17, srcv = v & 0x1FFFF;
        int pos = atomicAdd(&cur_l[dstl], 1);
        csr[base + pos] = srcv;
    }
}

// ---------------- combined weight/bias pack (+ bin_cnt zero) ----------------
// Storage perms: layer0 mem offset m (0..127) -> true col ((m&7)<<4)|(m>>3);
// layer1 mem offset m (0..63) -> true col ((m&3)<<4)|(m>>2).
__global__ void pack_k(const float* __restrict__ Wl0, const float* __restrict__ Wr0,
                       const float* __restrict__ Wl1, const float* __restrict__ Wr1,
                       const float* __restrict__ bl0, const float* __restrict__ bl1,
                       unsigned short* __restrict__ Bp0, unsigned short* __restrict__ Bp1,
                       float* __restrict__ b0p, float* __restrict__ b1p,
                       int* __restrict__ bin_cnt)
{
    int t = blockIdx.x * 256 + threadIdx.x;
    if (t < NBINS) bin_cnt[t] = 0;
    if (t < 4096) {                     // Bp0: (kt, n, q), ntot=256, ncl=128
        int q = t & 3;
        int n = (t >> 2) & 255;
        int kt = t >> 10;
        unsigned short o[8];
        #pragma unroll
        for (int j = 0; j < 8; ++j) {
            int k = kt * 32 + q * 8 + j;
            float v = (n < 128) ? Wl0[(size_t)k * 128 + n] : Wr0[(size_t)k * 128 + (n - 128)];
            o[j] = f2bf(v);
        }
        uint4 w;
        w.x = (unsigned)o[0] | ((unsigned)o[1] << 16);
        w.y = (unsigned)o[2] | ((unsigned)o[3] << 16);
        w.z = (unsigned)o[4] | ((unsigned)o[5] << 16);
        w.w = (unsigned)o[6] | ((unsigned)o[7] << 16);
        *(uint4*)(Bp0 + (size_t)t * 8) = w;
    } else if (t < 6144) {              // Bp1: ntot=128, ncl=64, h1-perm rows
        int u = t - 4096;
        int q = u & 3;
        int n = (u >> 2) & 127;
        int kt = u >> 9;
        unsigned short o[8];
        #pragma unroll
        for (int j = 0; j < 8; ++j) {
            int k = kt * 32 + q * 8 + j;          // h1 mem offset
            int c = ((k & 7) << 4) | (k >> 3);    // true column
            float v = (n < 64) ? Wl1[(size_t)c * 64 + n] : Wr1[(size_t)c * 64 + (n - 64)];
            o[j] = f2bf(v);
        }
        uint4 w;
        w.x = (unsigned)o[0] | ((unsigned)o[1] << 16);
        w.y = (unsigned)o[2] | ((unsigned)o[3] << 16);
        w.z = (unsigned)o[4] | ((unsigned)o[5] << 16);
        w.w = (unsigned)o[6] | ((unsigned)o[7] << 16);
        *(uint4*)(Bp1 + (size_t)u * 8) = w;
    } else if (t < 6144 + 128) {
        int m = t - 6144;
        b0p[m] = bl0[((m & 7) << 4) | (m >> 3)];
    } else if (t < 6144 + 192) {
        int m = t - 6272;
        b1p[m] = bl1[((m & 3) << 4) | (m >> 2)];
    }
}

// ---------------- MFMA GEMM: [t | r] = A @ [Wl | Wr], K=128 ----------------
// t-half stored fp8 e4m3 PERMUTED (mem m = ln*NTH + nt), r-half bf16 same perm.
template<int NCOLS, bool AFP32>
__global__ __launch_bounds__(256) void gemm_k(
    const void* __restrict__ Av, const unsigned short* __restrict__ Bp,
    unsigned char* __restrict__ Tout, unsigned short* __restrict__ Rout)
{
    constexpr int NT = NCOLS / 16;
    constexpr int NTH = NCOLS / 32;   // accs per half (8 for layer0, 4 for layer1)
    constexpr int HC = NCOLS / 2;     // cols per half
    int wave = threadIdx.x >> 6;
    int lane = threadIdx.x & 63;
    int ln = lane & 15, q = lane >> 4;
    int row0 = (blockIdx.x * 4 + wave) * 16;
    if (row0 >= NN) return;
    int arow = row0 + ln;

    f4_t acc[NT];
    #pragma unroll
    for (int nt = 0; nt < NT; ++nt) acc[nt] = (f4_t){0.f, 0.f, 0.f, 0.f};

    #pragma unroll
    for (int kt = 0; kt < 4; ++kt) {
        bf8_t a;
        if (AFP32) {
            const float* ap = (const float*)Av + (size_t)arow * 128 + kt * 32 + q * 8;
            f4_t a0 = *(const f4_t*)ap;
            f4_t a1 = *(const f4_t*)(ap + 4);
            #pragma unroll
            for (int j = 0; j < 4; ++j) {
                a[j]     = (short)f2bf(a0[j]);
                a[4 + j] = (short)f2bf(a1[j]);
            }
        } else {
            a = *(const bf8_t*)((const unsigned short*)Av + (size_t)arow * 128 + kt * 32 + q * 8);
        }
        const unsigned short* bb = Bp + (size_t)kt * NCOLS * 32 + (size_t)ln * 32 + q * 8;
        #pragma unroll
        for (int nt = 0; nt < NT; ++nt) {
            bf8_t b = *(const bf8_t*)(bb + nt * 512);
            acc[nt] = __builtin_amdgcn_mfma_f32_16x16x32_bf16(a, b, acc[nt], 0, 0, 0);
        }
    }

    #pragma unroll
    for (int r = 0; r < 4; ++r) {
        int row = row0 + q * 4 + r;
        if (NTH == 8) {
            uint2 wt;
            wt.x = pk4_fp8(acc[0][r], acc[1][r], acc[2][r], acc[3][r]);
            wt.y = pk4_fp8(acc[4][r], acc[5][r], acc[6][r], acc[7][r]);
            *(uint2*)(Tout + (size_t)row * HC + ln * 8) = wt;
            uint4 wr;
            wr.x = (unsigned)f2bf(acc[8][r])  | ((unsigned)f2bf(acc[9][r])  << 16);
            wr.y = (unsigned)f2bf(acc[10][r]) | ((unsigned)f2bf(acc[11][r]) << 16);
            wr.z = (unsigned)f2bf(acc[12][r]) | ((unsigned)f2bf(acc[13][r]) << 16);
            wr.w = (unsigned)f2bf(acc[14][r]) | ((unsigned)f2bf(acc[15][r]) << 16);
            *(uint4*)(Rout + (size_t)row * HC + ln * 8) = wr;
        } else {
            unsigned wt = pk4_fp8(acc[0][r], acc[1][r], acc[2][r], acc[3][r]);
            *(unsigned*)(Tout + (size_t)row * HC + ln * 4) = wt;
            uint2 wr;
            wr.x = (unsigned)f2bf(acc[4][r]) | ((unsigned)f2bf(acc[5][r]) << 16);
            wr.y = (unsigned)f2bf(acc[6][r]) | ((unsigned)f2bf(acc[7][r]) << 16);
            *(uint2*)(Rout + (size_t)row * HC + ln * 4) = wr;
        }
    }
}

// ---------------- fused gather-mean + combine ----------------
// t rows are fp8 (8<<LPNS bytes); r/h rows bf16 (8<<LPNS ushorts). Per lane: 8 cols.
__device__ __forceinline__ void unp8(float* a, uint4 v) {
    a[0] = bfl(v.x); a[1] = bfh(v.x);
    a[2] = bfl(v.y); a[3] = bfh(v.y);
    a[4] = bfl(v.z); a[5] = bfh(v.z);
    a[6] = bfl(v.w); a[7] = bfh(v.w);
}

template<int LPNS, bool RELU>
__global__ __launch_bounds__(256) void gather_fuse_k(
    const unsigned char* __restrict__ tq, const int* __restrict__ csr,
    const int* __restrict__ row_ptr, const float* __restrict__ invd,
    const unsigned short* __restrict__ rg, const float* __restrict__ biasp,
    unsigned short* __restrict__ hout)
{
    constexpr int STRIDE = 8 << LPNS;   // fp8 row bytes
    int t = blockIdx.x * 256 + threadIdx.x;
    int node = t >> LPNS;
    int lane = t & ((1 << LPNS) - 1);
    if (node >= NN) return;
    int e = row_ptr[node];
    int e1 = row_ptr[node + 1];
    const unsigned char* fb = tq + lane * 8;

    float a0[8] = {0.f, 0.f, 0.f, 0.f, 0.f, 0.f, 0.f, 0.f};
    float a1[8] = {0.f, 0.f, 0.f, 0.f, 0.f, 0.f, 0.f, 0.f};
    for (; e + 3 < e1; e += 4) {
        int s0 = csr[e], s1 = csr[e + 1], s2 = csr[e + 2], s3 = csr[e + 3];
        uint2 v0 = *(const uint2*)(fb + (size_t)s0 * STRIDE);
        uint2 v1 = *(const uint2*)(fb + (size_t)s1 * STRIDE);
        uint2 v2 = *(const uint2*)(fb + (size_t)s2 * STRIDE);
        uint2 v3 = *(const uint2*)(fb + (size_t)s3 * STRIDE);
        accf8(a0, v0); accf8(a1, v1); accf8(a0, v2); accf8(a1, v3);
    }
    for (; e < e1; ++e) {
        int s0 = csr[e];
        uint2 v0 = *(const uint2*)(fb + (size_t)s0 * STRIDE);
        accf8(a0, v0);
    }

    float inv = invd[node];
    uint4 rv = *(const uint4*)(rg + (size_t)node * STRIDE + lane * 8);
    float rr[8];
    unp8(rr, rv);
    f4_t b0 = *(const f4_t*)(biasp + lane * 8);
    f4_t b1 = *(const f4_t*)(biasp + lane * 8 + 4);
    float o[8];
    #pragma unroll
    for (int j = 0; j < 8; ++j) {
        float bj = (j < 4) ? b0[j] : b1[j - 4];
        float v = (a0[j] + a1[j]) * inv + rr[j] + bj;
        o[j] = RELU ? fmaxf(v, 0.f) : v;
    }
    uint4 w;
    w.x = (unsigned)f2bf(o[0]) | ((unsigned)f2bf(o[1]) << 16);
    w.y = (unsigned)f2bf(o[2]) | ((unsigned)f2bf(o[3]) << 16);
    w.z = (unsigned)f2bf(o[4]) | ((unsigned)f2bf(o[5]) << 16);
    w.w = (unsigned)f2bf(o[6]) | ((unsigned)f2bf(o[7]) << 16);
    *(uint4*)(hout + (size_t)node * STRIDE + lane * 8) = w;
}

// ---------------- edge scoring: 8 lanes x 8 bf16, 2 edges per group ----------------
__device__ __forceinline__ float dot8(uint4 va, uint4 vb) {
    return bfl(va.x) * bfl(vb.x) + bfh(va.x) * bfh(vb.x)
         + bfl(va.y) * bfl(vb.y) + bfh(va.y) * bfh(vb.y)
         + bfl(va.z) * bfl(vb.z) + bfh(va.z) * bfh(vb.z)
         + bfl(va.w) * bfl(vb.w) + bfh(va.w) * bfh(vb.w);
}

__global__ __launch_bounds__(256) void score_k(
    const unsigned short* __restrict__ h2b, const int* __restrict__ pos,
    const int* __restrict__ neg, float* __restrict__ out)
{
    int t = blockIdx.x * 256 + threadIdx.x;
    int g = t >> 3, l = t & 7;
    int eg0 = g * 2;
    if (eg0 >= 2 * EPE) return;
    int eg1 = eg0 + 1;
    int a0i, b0i, a1i, b1i;
    if (eg0 < EPE) { a0i = pos[eg0]; b0i = pos[EPE + eg0]; }
    else { int e2 = eg0 - EPE; a0i = neg[e2]; b0i = neg[EPE + e2]; }
    if (eg1 < EPE) { a1i = pos[eg1]; b1i = pos[EPE + eg1]; }
    else { int e2 = eg1 - EPE; a1i = neg[e2]; b1i = neg[EPE + e2]; }
    const unsigned short* hb = h2b + (size_t)l * 8;
    uint4 va0 = *(const uint4*)(hb + (size_t)a0i * 64);
    uint4 vb0 = *(const uint4*)(hb + (size_t)b0i * 64);
    uint4 va1 = *(const uint4*)(hb + (size_t)a1i * 64);
    uint4 vb1 = *(const uint4*)(hb + (size_t)b1i * 64);
    float p0 = dot8(va0, vb0);
    float p1 = dot8(va1, vb1);
    p0 += __shfl_xor(p0, 1, 8);
    p1 += __shfl_xor(p1, 1, 8);
    p0 += __shfl_xor(p0, 2, 8);
    p1 += __shfl_xor(p1, 2, 8);
    p0 += __shfl_xor(p0, 4, 8);
    p1 += __shfl_xor(p1, 4, 8);
    if (l == 0) { out[eg0] = p0; out[eg1] = p1; }
}

extern "C" void kernel_launch(void* const* d_in, const int* in_sizes, int n_in,
                              void* d_out, int out_size, void* d_ws, size_t ws_size,
                              hipStream_t stream) {
    const float* x   = (const float*)d_in[0];
    const int*   ei  = (const int*)d_in[1];
    const int*   pei = (const int*)d_in[2];
    const int*   nei = (const int*)d_in[3];
    const float* Wl0 = (const float*)d_in[4];
    const float* bl0 = (const float*)d_in[5];
    const float* Wr0 = (const float*)d_in[6];
    const float* Wl1 = (const float*)d_in[7];
    const float* bl1 = (const float*)d_in[8];
    const float* Wr1 = (const float*)d_in[9];
    float* out = (float*)d_out;

    char* ws = (char*)d_ws;
    size_t off = 0;
    auto alloc = [&](size_t bytes) {
        void* p = ws + off;
        off = (off + bytes + 255) & ~(size_t)255;
        return p;
    };
    float* invd     = (float*)alloc((size_t)NN * 4);
    int*   row_ptr  = (int*)  alloc((size_t)(NN + 1) * 4);
    int*   bin_cnt  = (int*)  alloc((size_t)NBINS * 4);
    int*   binbuf   = (int*)  alloc((size_t)NBINS * BCAP * 4);
    int*   csr      = (int*)  alloc((size_t)EE * 4);
    unsigned short* Bp0 = (unsigned short*)alloc((size_t)4096 * 8 * 2);
    unsigned short* Bp1 = (unsigned short*)alloc((size_t)2048 * 8 * 2);
    float* b0p = (float*)alloc(128 * 4);
    float* b1p = (float*)alloc(64 * 4);
    unsigned char*  t0q = (unsigned char*) alloc((size_t)NN * 128);      // fp8; t1q aliases
    unsigned short* r0b = (unsigned short*)alloc((size_t)NN * 128 * 2);  // r1b aliases
    unsigned short* h1b = (unsigned short*)alloc((size_t)NN * 128 * 2);  // h2b aliases
    unsigned char*  t1q = t0q;
    unsigned short* r1b = r0b;
    unsigned short* h2b = h1b;

    const int* src = ei;        // edge_index[0]
    const int* dst = ei + EE;   // edge_index[1]

    // pack (also zeroes bin_cnt) -> CSR build
    pack_k<<<25, 256, 0, stream>>>(Wl0, Wr0, Wl1, Wr1, bl0, bl1, Bp0, Bp1, b0p, b1p, bin_cnt);
    binpass1_k<<<NB1, 256, 0, stream>>>(src, dst, bin_cnt, binbuf);
    binpass2_k<<<NBINS, 256, 0, stream>>>(binbuf, bin_cnt, csr, row_ptr, invd);

    // layer 0: [t0 | r0] = x @ [Wl0 | Wr0]; h1 = relu(mean(t0) + r0 + b0)
    gemm_k<256, true><<<1563, 256, 0, stream>>>(x, Bp0, t0q, r0b);
    gather_fuse_k<4, true><<<(NN * 16 + 255) / 256, 256, 0, stream>>>(
        t0q, csr, row_ptr, invd, r0b, b0p, h1b);

    // layer 1: [t1 | r1] = h1 @ [Wl1 | Wr1]; h2 = mean(t1) + r1 + b1
    gemm_k<128, false><<<1563, 256, 0, stream>>>(h1b, Bp1, t1q, r1b);
    gather_fuse_k<3, false><<<(NN * 8 + 255) / 256, 256, 0, stream>>>(
        t1q, csr, row_ptr, invd, r1b, b1p, h2b);

    // scoring (2 edges per 8-lane group)
    score_k<<<(EPE * 8 + 255) / 256, 256, 0, stream>>>(h2b, pei, nei, out);
}

// Round 8
// 297.908 us; speedup vs baseline: 1.6229x; 1.0038x over previous
//
#include <hip/hip_runtime.h>

#define NN 100000
#define EE 1600000
#define EPE 500000
#define NBINS 196        // ceil(NN/512), bin = dst >> 9
#define BCAP 12288       // slots per bin (avg 8192, sigma ~90 -> huge margin)
#define EPB 2048         // edges per block in binpass1
#define NB1 782          // ceil(EE/EPB)

typedef short bf8_t __attribute__((ext_vector_type(8)));   // 8 x bf16 (4 VGPRs)
typedef float f4_t  __attribute__((ext_vector_type(4)));   // MFMA accumulator
typedef float f2v  __attribute__((ext_vector_type(2)));

__device__ __forceinline__ unsigned short f2bf(float f) {
    unsigned u = __float_as_uint(f);
    unsigned r = (u + 0x7fffu + ((u >> 16) & 1u)) >> 16;   // RNE
    return (unsigned short)r;
}
__device__ __forceinline__ float bfl(unsigned u) { return __uint_as_float(u << 16); }
__device__ __forceinline__ float bfh(unsigned u) { return __uint_as_float(u & 0xffff0000u); }

// storage perms (mem offset within half-row -> true col within half):
// layer0: wave-sub strip 64, NT=4:  col = (m>>6)*64 + (m&3)*16 + ((m>>2)&15)
// layer1: wave-sub strip 32, NT=2:  col = (m>>5)*32 + (m&1)*16 + ((m>>1)&15)
__device__ __forceinline__ int c0p(int m) {
    return ((m >> 6) & 1) * 64 + (m & 3) * 16 + ((m >> 2) & 15);
}
__device__ __forceinline__ int c1p(int m) {
    return ((m >> 5) & 1) * 32 + (m & 1) * 16 + ((m >> 1) & 15);
}

// ---------------- fp8 e4m3 encode/decode ----------------
#if __has_builtin(__builtin_amdgcn_cvt_pk_fp8_f32) && __has_builtin(__builtin_amdgcn_cvt_pk_f32_fp8)
__device__ __forceinline__ unsigned pk4_fp8(float a0, float a1, float a2, float a3) {
    int w = 0;
    w = __builtin_amdgcn_cvt_pk_fp8_f32(a0, a1, w, false);
    w = __builtin_amdgcn_cvt_pk_fp8_f32(a2, a3, w, true);
    return (unsigned)w;
}
__device__ __forceinline__ unsigned short pk2_fp8(float a0, float a1) {
    int w = __builtin_amdgcn_cvt_pk_fp8_f32(a0, a1, 0, false);
    return (unsigned short)(w & 0xffff);
}
__device__ __forceinline__ void accf8(float* a, uint2 v) {
    f2v p0 = __builtin_amdgcn_cvt_pk_f32_fp8((int)v.x, false);
    f2v p1 = __builtin_amdgcn_cvt_pk_f32_fp8((int)v.x, true);
    f2v p2 = __builtin_amdgcn_cvt_pk_f32_fp8((int)v.y, false);
    f2v p3 = __builtin_amdgcn_cvt_pk_f32_fp8((int)v.y, true);
    a[0] += p0.x; a[1] += p0.y; a[2] += p1.x; a[3] += p1.y;
    a[4] += p2.x; a[5] += p2.y; a[6] += p3.x; a[7] += p3.y;
}
#else
#include <hip/hip_fp8.h>
__device__ __forceinline__ unsigned pk4_fp8(float a0, float a1, float a2, float a3) {
    unsigned r;
    r  = (unsigned)__hip_cvt_float_to_fp8(a0, __HIP_SATFINITE, __HIP_E4M3);
    r |= (unsigned)__hip_cvt_float_to_fp8(a1, __HIP_SATFINITE, __HIP_E4M3) << 8;
    r |= (unsigned)__hip_cvt_float_to_fp8(a2, __HIP_SATFINITE, __HIP_E4M3) << 16;
    r |= (unsigned)__hip_cvt_float_to_fp8(a3, __HIP_SATFINITE, __HIP_E4M3) << 24;
    return r;
}
__device__ __forceinline__ unsigned short pk2_fp8(float a0, float a1) {
    unsigned r;
    r  = (unsigned)__hip_cvt_float_to_fp8(a0, __HIP_SATFINITE, __HIP_E4M3);
    r |= (unsigned)__hip_cvt_float_to_fp8(a1, __HIP_SATFINITE, __HIP_E4M3) << 8;
    return (unsigned short)r;
}
__device__ __forceinline__ float dec1_fp8(unsigned b) {
    __hip_fp8_e4m3 h; h.__x = (__hip_fp8_storage_t)(b & 0xff);
    return (float)h;
}
__device__ __forceinline__ void accf8(float* a, uint2 v) {
    a[0] += dec1_fp8(v.x); a[1] += dec1_fp8(v.x >> 8);
    a[2] += dec1_fp8(v.x >> 16); a[3] += dec1_fp8(v.x >> 24);
    a[4] += dec1_fp8(v.y); a[5] += dec1_fp8(v.y >> 8);
    a[6] += dec1_fp8(v.y >> 16); a[7] += dec1_fp8(v.y >> 24);
}
#endif

// ---------------- binned CSR build ----------------
__global__ __launch_bounds__(256) void binpass1_k(
    const int* __restrict__ src, const int* __restrict__ dst,
    int* __restrict__ bin_cnt, int* __restrict__ binbuf)
{
    __shared__ int cnt_l[NBINS];
    __shared__ int base_l[NBINS];
    int tid = threadIdx.x;
    int e0 = blockIdx.x * EPB;
    for (int i = tid; i < NBINS; i += 256) cnt_l[i] = 0;
    __syncthreads();

    int pk[8];
    #pragma unroll
    for (int i = 0; i < 8; ++i) {
        int e = e0 + tid + i * 256;
        pk[i] = -1;
        if (e < EE) {
            int d = dst[e];
            int b = d >> 9;
            int r = atomicAdd(&cnt_l[b], 1);        // r < 2048
            pk[i] = (b << 20) | ((d & 511) << 11) | r;
        }
    }
    __syncthreads();
    for (int i = tid; i < NBINS; i += 256)
        base_l[i] = atomicAdd(&bin_cnt[i], cnt_l[i]);
    __syncthreads();

    #pragma unroll
    for (int i = 0; i < 8; ++i) {
        int e = e0 + tid + i * 256;
        if (e >= EE) continue;
        int v = pk[i];
        int b = v >> 20, dl = (v >> 11) & 511, r = v & 2047;
        binbuf[b * BCAP + base_l[b] + r] = (dl << 17) | src[e];  // src<2^17
    }
}

__global__ __launch_bounds__(256) void binpass2_k(
    const int* __restrict__ binbuf, const int* __restrict__ bin_cnt,
    int* __restrict__ csr, int* __restrict__ row_ptr, float* __restrict__ invd)
{
    __shared__ int deg_l[512];
    __shared__ int off_l[512];
    __shared__ int cur_l[512];
    __shared__ int s[256];
    int tid = threadIdx.x;
    int b = blockIdx.x;
    int lo = b << 9;
    int n_here = min(512, NN - lo);

    int bc = (tid < NBINS) ? bin_cnt[tid] : 0;
    s[tid] = bc;
    __syncthreads();
    #pragma unroll
    for (int off = 1; off < 256; off <<= 1) {
        int t = (tid >= off) ? s[tid - off] : 0;
        __syncthreads();
        s[tid] += t;
        __syncthreads();
    }
    int base = (b == 0) ? 0 : s[b - 1];
    int cnt = bin_cnt[b];
    const int* bb = binbuf + b * BCAP;
    __syncthreads();

    deg_l[tid] = 0; deg_l[tid + 256] = 0;
    __syncthreads();
    for (int i = tid; i < cnt; i += 256)
        atomicAdd(&deg_l[bb[i] >> 17], 1);
    __syncthreads();

    int a0 = deg_l[2 * tid], a1 = deg_l[2 * tid + 1];
    s[tid] = a0 + a1;
    __syncthreads();
    #pragma unroll
    for (int off = 1; off < 256; off <<= 1) {
        int t = (tid >= off) ? s[tid - off] : 0;
        __syncthreads();
        s[tid] += t;
        __syncthreads();
    }
    int excl = s[tid] - (a0 + a1);
    off_l[2 * tid] = excl;
    off_l[2 * tid + 1] = excl + a0;
    cur_l[2 * tid] = excl;
    cur_l[2 * tid + 1] = excl + a0;
    __syncthreads();

    for (int j = tid; j < n_here; j += 256) {
        row_ptr[lo + j] = base + off_l[j];
        invd[lo + j] = 1.0f / fmaxf((float)deg_l[j], 1.0f);
    }
    if (tid == 0 && b == NBINS - 1) row_ptr[NN] = EE;

    for (int i = tid; i < cnt; i += 256) {
        int v = bb[i];
        int dstl = v >> 17, srcv = v & 0x1FFFF;
        int pos = atomicAdd(&cur_l[dstl], 1);
        csr[base + pos] = srcv;
    }
}

// ---------------- combined weight/bias pack (+ bin_cnt zero) ----------------
__global__ void pack_k(const float* __restrict__ Wl0, const float* __restrict__ Wr0,
                       const float* __restrict__ Wl1, const float* __restrict__ Wr1,
                       const float* __restrict__ bl0, const float* __restrict__ bl1,
                       unsigned short* __restrict__ Bp0, unsigned short* __restrict__ Bp1,
                       float* __restrict__ b0p, float* __restrict__ b1p,
                       int* __restrict__ bin_cnt)
{
    int t = blockIdx.x * 256 + threadIdx.x;
    if (t < NBINS) bin_cnt[t] = 0;
    if (t < 4096) {                     // Bp0: (kt, n, q), ntot=256, ncl=128
        int q = t & 3;
        int n = (t >> 2) & 255;
        int kt = t >> 10;
        unsigned short o[8];
        #pragma unroll
        for (int j = 0; j < 8; ++j) {
            int k = kt * 32 + q * 8 + j;
            float v = (n < 128) ? Wl0[(size_t)k * 128 + n] : Wr0[(size_t)k * 128 + (n - 128)];
            o[j] = f2bf(v);
        }
        uint4 w;
        w.x = (unsigned)o[0] | ((unsigned)o[1] << 16);
        w.y = (unsigned)o[2] | ((unsigned)o[3] << 16);
        w.z = (unsigned)o[4] | ((unsigned)o[5] << 16);
        w.w = (unsigned)o[6] | ((unsigned)o[7] << 16);
        *(uint4*)(Bp0 + (size_t)t * 8) = w;
    } else if (t < 6144) {              // Bp1: ntot=128, ncl=64, h1-perm rows
        int u = t - 4096;
        int q = u & 3;
        int n = (u >> 2) & 127;
        int kt = u >> 9;
        unsigned short o[8];
        #pragma unroll
        for (int j = 0; j < 8; ++j) {
            int k = kt * 32 + q * 8 + j;          // h1 mem offset
            int c = c0p(k);                       // true column
            float v = (n < 64) ? Wl1[(size_t)c * 64 + n] : Wr1[(size_t)c * 64 + (n - 64)];
            o[j] = f2bf(v);
        }
        uint4 w;
        w.x = (unsigned)o[0] | ((unsigned)o[1] << 16);
        w.y = (unsigned)o[2] | ((unsigned)o[3] << 16);
        w.z = (unsigned)o[4] | ((unsigned)o[5] << 16);
        w.w = (unsigned)o[6] | ((unsigned)o[7] << 16);
        *(uint4*)(Bp1 + (size_t)u * 8) = w;
    } else if (t < 6144 + 128) {
        int m = t - 6144;
        b0p[m] = bl0[c0p(m)];
    } else if (t < 6144 + 192) {
        int m = t - 6272;
        b1p[m] = bl1[c1p(m)];
    }
}

// ---------------- MFMA GEMM: [t | r] = A @ [Wl | Wr], K=128 ----------------
// Wave = 64-row x (NCOLS/4)-col strip. B fragments hoisted into registers
// (waves 0,1 -> t half / fp8 out; waves 2,3 -> r half / bf16 out).
// t-half mem offset m = wsub*STRIP + ln*NT + nt -> true col wsub*STRIP+nt*16+ln.
template<int NCOLS, bool AFP32>
__global__ __launch_bounds__(256) void gemm_k(
    const void* __restrict__ Av, const unsigned short* __restrict__ Bp,
    unsigned char* __restrict__ Tout, unsigned short* __restrict__ Rout)
{
    constexpr int STRIP = NCOLS / 4;
    constexpr int NT = STRIP / 16;    // 4 (layer0) or 2 (layer1)
    constexpr int HC = NCOLS / 2;
    int w = threadIdx.x >> 6;
    int lane = threadIdx.x & 63;
    int ln = lane & 15, q = lane >> 4;
    int half = w >> 1, wsub = w & 1;
    int row0 = blockIdx.x * 64;
    int colbase = half * HC + wsub * STRIP;

    // hoist B fragments for this wave's strip
    bf8_t Bf[4][NT];
    #pragma unroll
    for (int kt = 0; kt < 4; ++kt)
        #pragma unroll
        for (int nt = 0; nt < NT; ++nt)
            Bf[kt][nt] = *(const bf8_t*)(Bp + (size_t)kt * NCOLS * 32
                                         + (size_t)(colbase + nt * 16 + ln) * 32 + q * 8);

    for (int rt = 0; rt < 4; ++rt) {
        int rowt = row0 + rt * 16;
        if (rowt >= NN) break;        // NN % 16 == 0: tiles fully valid or absent
        int arow = rowt + ln;

        bf8_t Af[4];
        if (AFP32) {
            #pragma unroll
            for (int kt = 0; kt < 4; ++kt) {
                const float* ap = (const float*)Av + (size_t)arow * 128 + kt * 32 + q * 8;
                f4_t a0 = *(const f4_t*)ap;
                f4_t a1 = *(const f4_t*)(ap + 4);
                #pragma unroll
                for (int j = 0; j < 4; ++j) {
                    Af[kt][j]     = (short)f2bf(a0[j]);
                    Af[kt][4 + j] = (short)f2bf(a1[j]);
                }
            }
        } else {
            #pragma unroll
            for (int kt = 0; kt < 4; ++kt)
                Af[kt] = *(const bf8_t*)((const unsigned short*)Av
                                         + (size_t)arow * 128 + kt * 32 + q * 8);
        }

        f4_t acc[NT];
        #pragma unroll
        for (int nt = 0; nt < NT; ++nt) acc[nt] = (f4_t){0.f, 0.f, 0.f, 0.f};
        #pragma unroll
        for (int kt = 0; kt < 4; ++kt)
            #pragma unroll
            for (int nt = 0; nt < NT; ++nt)
                acc[nt] = __builtin_amdgcn_mfma_f32_16x16x32_bf16(Af[kt], Bf[kt][nt], acc[nt], 0, 0, 0);

        #pragma unroll
        for (int r = 0; r < 4; ++r) {
            int row = rowt + q * 4 + r;
            if (half == 0) {     // fp8 t-half
                if (NT == 4) {
                    unsigned v = pk4_fp8(acc[0][r], acc[1][r], acc[2][r], acc[3][r]);
                    *(unsigned*)(Tout + (size_t)row * HC + wsub * 64 + ln * 4) = v;
                } else {
                    unsigned short v = pk2_fp8(acc[0][r], acc[1][r]);
                    *(unsigned short*)(Tout + (size_t)row * HC + wsub * 32 + ln * 2) = v;
                }
            } else {             // bf16 r-half
                if (NT == 4) {
                    uint2 v;
                    v.x = (unsigned)f2bf(acc[0][r]) | ((unsigned)f2bf(acc[1][r]) << 16);
                    v.y = (unsigned)f2bf(acc[2][r]) | ((unsigned)f2bf(acc[3][r]) << 16);
                    *(uint2*)(Rout + (size_t)row * HC + wsub * 64 + ln * 4) = v;
                } else {
                    unsigned v = (unsigned)f2bf(acc[0][r]) | ((unsigned)f2bf(acc[1][r]) << 16);
                    *(unsigned*)(Rout + (size_t)row * HC + wsub * 32 + ln * 2) = v;
                }
            }
        }
    }
}

// ---------------- fused gather-mean + combine ----------------
__device__ __forceinline__ void unp8(float* a, uint4 v) {
    a[0] = bfl(v.x); a[1] = bfh(v.x);
    a[2] = bfl(v.y); a[3] = bfh(v.y);
    a[4] = bfl(v.z); a[5] = bfh(v.z);
    a[6] = bfl(v.w); a[7] = bfh(v.w);
}

template<int LPNS, bool RELU>
__global__ __launch_bounds__(256) void gather_fuse_k(
    const unsigned char* __restrict__ tq, const int* __restrict__ csr,
    const int* __restrict__ row_ptr, const float* __restrict__ invd,
    const unsigned short* __restrict__ rg, const float* __restrict__ biasp,
    unsigned short* __restrict__ hout)
{
    constexpr int STRIDE = 8 << LPNS;   // fp8 row bytes
    int t = blockIdx.x * 256 + threadIdx.x;
    int node = t >> LPNS;
    int lane = t & ((1 << LPNS) - 1);
    if (node >= NN) return;
    int e = row_ptr[node];
    int e1 = row_ptr[node + 1];
    const unsigned char* fb = tq + lane * 8;

    float a0[8] = {0.f, 0.f, 0.f, 0.f, 0.f, 0.f, 0.f, 0.f};
    float a1[8] = {0.f, 0.f, 0.f, 0.f, 0.f, 0.f, 0.f, 0.f};
    for (; e + 3 < e1; e += 4) {
        int s0 = csr[e], s1 = csr[e + 1], s2 = csr[e + 2], s3 = csr[e + 3];
        uint2 v0 = *(const uint2*)(fb + (size_t)s0 * STRIDE);
        uint2 v1 = *(const uint2*)(fb + (size_t)s1 * STRIDE);
        uint2 v2 = *(const uint2*)(fb + (size_t)s2 * STRIDE);
        uint2 v3 = *(const uint2*)(fb + (size_t)s3 * STRIDE);
        accf8(a0, v0); accf8(a1, v1); accf8(a0, v2); accf8(a1, v3);
    }
    for (; e < e1; ++e) {
        int s0 = csr[e];
        uint2 v0 = *(const uint2*)(fb + (size_t)s0 * STRIDE);
        accf8(a0, v0);
    }

    float inv = invd[node];
    uint4 rv = *(const uint4*)(rg + (size_t)node * STRIDE + lane * 8);
    float rr[8];
    unp8(rr, rv);
    f4_t b0 = *(const f4_t*)(biasp + lane * 8);
    f4_t b1 = *(const f4_t*)(biasp + lane * 8 + 4);
    float o[8];
    #pragma unroll
    for (int j = 0; j < 8; ++j) {
        float bj = (j < 4) ? b0[j] : b1[j - 4];
        float v = (a0[j] + a1[j]) * inv + rr[j] + bj;
        o[j] = RELU ? fmaxf(v, 0.f) : v;
    }
    uint4 w;
    w.x = (unsigned)f2bf(o[0]) | ((unsigned)f2bf(o[1]) << 16);
    w.y = (unsigned)f2bf(o[2]) | ((unsigned)f2bf(o[3]) << 16);
    w.z = (unsigned)f2bf(o[4]) | ((unsigned)f2bf(o[5]) << 16);
    w.w = (unsigned)f2bf(o[6]) | ((unsigned)f2bf(o[7]) << 16);
    *(uint4*)(hout + (size_t)node * STRIDE + lane * 8) = w;
}

// ---------------- edge scoring: 8 lanes x 8 bf16, 2 edges per group ----------------
__device__ __forceinline__ float dot8(uint4 va, uint4 vb) {
    return bfl(va.x) * bfl(vb.x) + bfh(va.x) * bfh(vb.x)
         + bfl(va.y) * bfl(vb.y) + bfh(va.y) * bfh(vb.y)
         + bfl(va.z) * bfl(vb.z) + bfh(va.z) * bfh(vb.z)
         + bfl(va.w) * bfl(vb.w) + bfh(va.w) * bfh(vb.w);
}

__global__ __launch_bounds__(256) void score_k(
    const unsigned short* __restrict__ h2b, const int* __restrict__ pos,
    const int* __restrict__ neg, float* __restrict__ out)
{
    int t = blockIdx.x * 256 + threadIdx.x;
    int g = t >> 3, l = t & 7;
    int eg0 = g * 2;
    if (eg0 >= 2 * EPE) return;
    int eg1 = eg0 + 1;
    int a0i, b0i, a1i, b1i;
    if (eg0 < EPE) { a0i = pos[eg0]; b0i = pos[EPE + eg0]; }
    else { int e2 = eg0 - EPE; a0i = neg[e2]; b0i = neg[EPE + e2]; }
    if (eg1 < EPE) { a1i = pos[eg1]; b1i = pos[EPE + eg1]; }
    else { int e2 = eg1 - EPE; a1i = neg[e2]; b1i = neg[EPE + e2]; }
    const unsigned short* hb = h2b + (size_t)l * 8;
    uint4 va0 = *(const uint4*)(hb + (size_t)a0i * 64);
    uint4 vb0 = *(const uint4*)(hb + (size_t)b0i * 64);
    uint4 va1 = *(const uint4*)(hb + (size_t)a1i * 64);
    uint4 vb1 = *(const uint4*)(hb + (size_t)b1i * 64);
    float p0 = dot8(va0, vb0);
    float p1 = dot8(va1, vb1);
    p0 += __shfl_xor(p0, 1, 8);
    p1 += __shfl_xor(p1, 1, 8);
    p0 += __shfl_xor(p0, 2, 8);
    p1 += __shfl_xor(p1, 2, 8);
    p0 += __shfl_xor(p0, 4, 8);
    p1 += __shfl_xor(p1, 4, 8);
    if (l == 0) { out[eg0] = p0; out[eg1] = p1; }
}

extern "C" void kernel_launch(void* const* d_in, const int* in_sizes, int n_in,
                              void* d_out, int out_size, void* d_ws, size_t ws_size,
                              hipStream_t stream) {
    const float* x   = (const float*)d_in[0];
    const int*   ei  = (const int*)d_in[1];
    const int*   pei = (const int*)d_in[2];
    const int*   nei = (const int*)d_in[3];
    const float* Wl0 = (const float*)d_in[4];
    const float* bl0 = (const float*)d_in[5];
    const float* Wr0 = (const float*)d_in[6];
    const float* Wl1 = (const float*)d_in[7];
    const float* bl1 = (const float*)d_in[8];
    const float* Wr1 = (const float*)d_in[9];
    float* out = (float*)d_out;

    char* ws = (char*)d_ws;
    size_t off = 0;
    auto alloc = [&](size_t bytes) {
        void* p = ws + off;
        off = (off + bytes + 255) & ~(size_t)255;
        return p;
    };
    float* invd     = (float*)alloc((size_t)NN * 4);
    int*   row_ptr  = (int*)  alloc((size_t)(NN + 1) * 4);
    int*   bin_cnt  = (int*)  alloc((size_t)NBINS * 4);
    int*   binbuf   = (int*)  alloc((size_t)NBINS * BCAP * 4);
    int*   csr      = (int*)  alloc((size_t)EE * 4);
    unsigned short* Bp0 = (unsigned short*)alloc((size_t)4096 * 8 * 2);
    unsigned short* Bp1 = (unsigned short*)alloc((size_t)2048 * 8 * 2);
    float* b0p = (float*)alloc(128 * 4);
    float* b1p = (float*)alloc(64 * 4);
    unsigned char*  t0q = (unsigned char*) alloc((size_t)NN * 128);      // fp8; t1q aliases
    unsigned short* r0b = (unsigned short*)alloc((size_t)NN * 128 * 2);  // r1b aliases
    unsigned short* h1b = (unsigned short*)alloc((size_t)NN * 128 * 2);  // h2b aliases
    unsigned char*  t1q = t0q;
    unsigned short* r1b = r0b;
    unsigned short* h2b = h1b;

    const int* src = ei;        // edge_index[0]
    const int* dst = ei + EE;   // edge_index[1]

    // pack (also zeroes bin_cnt) -> CSR build
    pack_k<<<25, 256, 0, stream>>>(Wl0, Wr0, Wl1, Wr1, bl0, bl1, Bp0, Bp1, b0p, b1p, bin_cnt);
    binpass1_k<<<NB1, 256, 0, stream>>>(src, dst, bin_cnt, binbuf);
    binpass2_k<<<NBINS, 256, 0, stream>>>(binbuf, bin_cnt, csr, row_ptr, invd);

    // layer 0: [t0 | r0] = x @ [Wl0 | Wr0]; h1 = relu(mean(t0) + r0 + b0)
    gemm_k<256, true><<<1563, 256, 0, stream>>>(x, Bp0, t0q, r0b);
    gather_fuse_k<4, true><<<(NN * 16 + 255) / 256, 256, 0, stream>>>(
        t0q, csr, row_ptr, invd, r0b, b0p, h1b);

    // layer 1: [t1 | r1] = h1 @ [Wl1 | Wr1]; h2 = mean(t1) + r1 + b1
    gemm_k<128, false><<<1563, 256, 0, stream>>>(h1b, Bp1, t1q, r1b);
    gather_fuse_k<3, false><<<(NN * 8 + 255) / 256, 256, 0, stream>>>(
        t1q, csr, row_ptr, invd, r1b, b1p, h2b);

    // scoring (2 edges per 8-lane group)
    score_k<<<(EPE * 8 + 255) / 256, 256, 0, stream>>>(h2b, pei, nei, out);
}

// Round 10
// 284.258 us; speedup vs baseline: 1.7008x; 1.0480x over previous
//
#include <hip/hip_runtime.h>

#define NN 100000
#define EE 1600000
#define EPE 500000
#define NBINS 196        // ceil(NN/512), bin = dst >> 9
#define BCAP 12288       // slots per bin
#define EPB 2048         // edges per block in binpass1
#define NB1 782          // ceil(EE/EPB)
#define GEMMB 782        // gemm blocks: ceil(NN/128)
#define CONVB 6250       // x->bf16 blocks: NN*128/(256*8)

typedef short bf8_t __attribute__((ext_vector_type(8)));   // 8 x bf16 (4 VGPRs)
typedef float f4_t  __attribute__((ext_vector_type(4)));   // MFMA accumulator
typedef float f2v  __attribute__((ext_vector_type(2)));

__device__ __forceinline__ unsigned short f2bf(float f) {
    unsigned u = __float_as_uint(f);
    unsigned r = (u + 0x7fffu + ((u >> 16) & 1u)) >> 16;   // RNE
    return (unsigned short)r;
}
__device__ __forceinline__ float bfl(unsigned u) { return __uint_as_float(u << 16); }
__device__ __forceinline__ float bfh(unsigned u) { return __uint_as_float(u & 0xffff0000u); }

// storage perms (mem offset within half-row -> true col within half):
__device__ __forceinline__ int c0p(int m) {
    return ((m >> 6) & 1) * 64 + (m & 3) * 16 + ((m >> 2) & 15);
}
__device__ __forceinline__ int c1p(int m) {
    return ((m >> 5) & 1) * 32 + (m & 1) * 16 + ((m >> 1) & 15);
}

// ---------------- fp8 e4m3 (t0/t1 message tensors ONLY — h2 stays bf16,
// fp8 h2 failed accuracy in R9: absmax 0.203 > 0.16) ----------------
#if __has_builtin(__builtin_amdgcn_cvt_pk_fp8_f32) && __has_builtin(__builtin_amdgcn_cvt_pk_f32_fp8)
__device__ __forceinline__ unsigned pk4_fp8(float a0, float a1, float a2, float a3) {
    int w = 0;
    w = __builtin_amdgcn_cvt_pk_fp8_f32(a0, a1, w, false);
    w = __builtin_amdgcn_cvt_pk_fp8_f32(a2, a3, w, true);
    return (unsigned)w;
}
__device__ __forceinline__ unsigned short pk2_fp8(float a0, float a1) {
    int w = __builtin_amdgcn_cvt_pk_fp8_f32(a0, a1, 0, false);
    return (unsigned short)(w & 0xffff);
}
__device__ __forceinline__ void accf8(float* a, uint2 v) {
    f2v p0 = __builtin_amdgcn_cvt_pk_f32_fp8((int)v.x, false);
    f2v p1 = __builtin_amdgcn_cvt_pk_f32_fp8((int)v.x, true);
    f2v p2 = __builtin_amdgcn_cvt_pk_f32_fp8((int)v.y, false);
    f2v p3 = __builtin_amdgcn_cvt_pk_f32_fp8((int)v.y, true);
    a[0] += p0.x; a[1] += p0.y; a[2] += p1.x; a[3] += p1.y;
    a[4] += p2.x; a[5] += p2.y; a[6] += p3.x; a[7] += p3.y;
}
#else
#include <hip/hip_fp8.h>
__device__ __forceinline__ unsigned pk4_fp8(float a0, float a1, float a2, float a3) {
    unsigned r;
    r  = (unsigned)__hip_cvt_float_to_fp8(a0, __HIP_SATFINITE, __HIP_E4M3);
    r |= (unsigned)__hip_cvt_float_to_fp8(a1, __HIP_SATFINITE, __HIP_E4M3) << 8;
    r |= (unsigned)__hip_cvt_float_to_fp8(a2, __HIP_SATFINITE, __HIP_E4M3) << 16;
    r |= (unsigned)__hip_cvt_float_to_fp8(a3, __HIP_SATFINITE, __HIP_E4M3) << 24;
    return r;
}
__device__ __forceinline__ unsigned short pk2_fp8(float a0, float a1) {
    unsigned r;
    r  = (unsigned)__hip_cvt_float_to_fp8(a0, __HIP_SATFINITE, __HIP_E4M3);
    r |= (unsigned)__hip_cvt_float_to_fp8(a1, __HIP_SATFINITE, __HIP_E4M3) << 8;
    return (unsigned short)r;
}
__device__ __forceinline__ float dec1_fp8(unsigned b) {
    __hip_fp8_e4m3 h; h.__x = (__hip_fp8_storage_t)(b & 0xff);
    return (float)h;
}
__device__ __forceinline__ void accf8(float* a, uint2 v) {
    a[0] += dec1_fp8(v.x); a[1] += dec1_fp8(v.x >> 8);
    a[2] += dec1_fp8(v.x >> 16); a[3] += dec1_fp8(v.x >> 24);
    a[4] += dec1_fp8(v.y); a[5] += dec1_fp8(v.y >> 8);
    a[6] += dec1_fp8(v.y >> 16); a[7] += dec1_fp8(v.y >> 24);
}
#endif

// ---------------- phase bodies ----------------
__device__ void binpass1_body(int blk, const int* __restrict__ src,
                              const int* __restrict__ dst,
                              int* __restrict__ bin_cnt, int* __restrict__ binbuf)
{
    __shared__ int cnt_l[NBINS];
    __shared__ int base_l[NBINS];
    int tid = threadIdx.x;
    int e0 = blk * EPB;
    for (int i = tid; i < NBINS; i += 256) cnt_l[i] = 0;
    __syncthreads();

    int pk[8];
    #pragma unroll
    for (int i = 0; i < 8; ++i) {
        int e = e0 + tid + i * 256;
        pk[i] = -1;
        if (e < EE) {
            int d = dst[e];
            int b = d >> 9;
            int r = atomicAdd(&cnt_l[b], 1);
            pk[i] = (b << 20) | ((d & 511) << 11) | r;
        }
    }
    __syncthreads();
    for (int i = tid; i < NBINS; i += 256)
        base_l[i] = atomicAdd(&bin_cnt[i], cnt_l[i]);
    __syncthreads();

    #pragma unroll
    for (int i = 0; i < 8; ++i) {
        int e = e0 + tid + i * 256;
        if (e >= EE) continue;
        int v = pk[i];
        int b = v >> 20, dl = (v >> 11) & 511, r = v & 2047;
        binbuf[b * BCAP + base_l[b] + r] = (dl << 17) | src[e];
    }
}

__device__ void binpass2_body(int b, const int* __restrict__ binbuf,
                              const int* __restrict__ bin_cnt, int* __restrict__ csr,
                              int* __restrict__ row_ptr, float* __restrict__ invd)
{
    __shared__ int deg_l[512];
    __shared__ int off_l[512];
    __shared__ int cur_l[512];
    __shared__ int s[256];
    int tid = threadIdx.x;
    int lo = b << 9;
    int n_here = min(512, NN - lo);

    int bc = (tid < NBINS) ? bin_cnt[tid] : 0;
    s[tid] = bc;
    __syncthreads();
    #pragma unroll
    for (int off = 1; off < 256; off <<= 1) {
        int t = (tid >= off) ? s[tid - off] : 0;
        __syncthreads();
        s[tid] += t;
        __syncthreads();
    }
    int base = (b == 0) ? 0 : s[b - 1];
    int cnt = bin_cnt[b];
    const int* bb = binbuf + b * BCAP;
    __syncthreads();

    deg_l[tid] = 0; deg_l[tid + 256] = 0;
    __syncthreads();
    for (int i = tid; i < cnt; i += 256)
        atomicAdd(&deg_l[bb[i] >> 17], 1);
    __syncthreads();

    int a0 = deg_l[2 * tid], a1 = deg_l[2 * tid + 1];
    s[tid] = a0 + a1;
    __syncthreads();
    #pragma unroll
    for (int off = 1; off < 256; off <<= 1) {
        int t = (tid >= off) ? s[tid - off] : 0;
        __syncthreads();
        s[tid] += t;
        __syncthreads();
    }
    int excl = s[tid] - (a0 + a1);
    off_l[2 * tid] = excl;
    off_l[2 * tid + 1] = excl + a0;
    cur_l[2 * tid] = excl;
    cur_l[2 * tid + 1] = excl + a0;
    __syncthreads();

    for (int j = tid; j < n_here; j += 256) {
        row_ptr[lo + j] = base + off_l[j];
        invd[lo + j] = 1.0f / fmaxf((float)deg_l[j], 1.0f);
    }
    if (tid == 0 && b == NBINS - 1) row_ptr[NN] = EE;

    for (int i = tid; i < cnt; i += 256) {
        int v = bb[i];
        int dstl = v >> 17, srcv = v & 0x1FFFF;
        int pos = atomicAdd(&cur_l[dstl], 1);
        csr[base + pos] = srcv;
    }
}

__device__ void pack_body(int blk, const float* __restrict__ Wl0, const float* __restrict__ Wr0,
                          const float* __restrict__ Wl1, const float* __restrict__ Wr1,
                          const float* __restrict__ bl0, const float* __restrict__ bl1,
                          unsigned short* __restrict__ Bp0, unsigned short* __restrict__ Bp1,
                          float* __restrict__ b0p, float* __restrict__ b1p)
{
    int t = blk * 256 + threadIdx.x;
    if (t < 4096) {                     // Bp0: (kt, n, q), ntot=256, ncl=128
        int q = t & 3;
        int n = (t >> 2) & 255;
        int kt = t >> 10;
        unsigned short o[8];
        #pragma unroll
        for (int j = 0; j < 8; ++j) {
            int k = kt * 32 + q * 8 + j;
            float v = (n < 128) ? Wl0[(size_t)k * 128 + n] : Wr0[(size_t)k * 128 + (n - 128)];
            o[j] = f2bf(v);
        }
        uint4 w;
        w.x = (unsigned)o[0] | ((unsigned)o[1] << 16);
        w.y = (unsigned)o[2] | ((unsigned)o[3] << 16);
        w.z = (unsigned)o[4] | ((unsigned)o[5] << 16);
        w.w = (unsigned)o[6] | ((unsigned)o[7] << 16);
        *(uint4*)(Bp0 + (size_t)t * 8) = w;
    } else if (t < 6144) {              // Bp1: ntot=128, ncl=64, h1-perm rows
        int u = t - 4096;
        int q = u & 3;
        int n = (u >> 2) & 127;
        int kt = u >> 9;
        unsigned short o[8];
        #pragma unroll
        for (int j = 0; j < 8; ++j) {
            int k = kt * 32 + q * 8 + j;          // h1 mem offset
            int c = c0p(k);                       // true column
            float v = (n < 64) ? Wl1[(size_t)c * 64 + n] : Wr1[(size_t)c * 64 + (n - 64)];
            o[j] = f2bf(v);
        }
        uint4 w;
        w.x = (unsigned)o[0] | ((unsigned)o[1] << 16);
        w.y = (unsigned)o[2] | ((unsigned)o[3] << 16);
        w.z = (unsigned)o[4] | ((unsigned)o[5] << 16);
        w.w = (unsigned)o[6] | ((unsigned)o[7] << 16);
        *(uint4*)(Bp1 + (size_t)u * 8) = w;
    } else if (t < 6144 + 128) {
        int m = t - 6144;
        b0p[m] = bl0[c0p(m)];
    } else if (t < 6144 + 192) {
        int m = t - 6272;
        b1p[m] = bl1[c1p(m)];
    }
}

__device__ void conv_body(int blk, const float* __restrict__ x, unsigned short* __restrict__ xb)
{
    int i = blk * 256 + threadIdx.x;       // 8 floats per thread, exact fit
    const float4* xp = (const float4*)x + (size_t)i * 2;
    float4 a = xp[0], b = xp[1];
    uint4 w;
    w.x = (unsigned)f2bf(a.x) | ((unsigned)f2bf(a.y) << 16);
    w.y = (unsigned)f2bf(a.z) | ((unsigned)f2bf(a.w) << 16);
    w.z = (unsigned)f2bf(b.x) | ((unsigned)f2bf(b.y) << 16);
    w.w = (unsigned)f2bf(b.z) | ((unsigned)f2bf(b.w) << 16);
    *(uint4*)(xb + (size_t)i * 8) = w;
}

// ---------------- MFMA GEMM body: [t | r] = A @ [Wl | Wr], K=128, 128 rows/block ----------------
template<int NCOLS>
__device__ __forceinline__ void gemm_body(
    int blk, const unsigned short* __restrict__ Ab, const unsigned short* __restrict__ Bp,
    unsigned char* __restrict__ Tout, unsigned short* __restrict__ Rout)
{
    constexpr int STRIP = NCOLS / 4;
    constexpr int NT = STRIP / 16;    // 4 (layer0) or 2 (layer1)
    constexpr int HC = NCOLS / 2;
    int w = threadIdx.x >> 6;
    int lane = threadIdx.x & 63;
    int ln = lane & 15, q = lane >> 4;
    int half = w >> 1, wsub = w & 1;
    int row0 = blk * 128;
    int colbase = half * HC + wsub * STRIP;

    bf8_t Bf[4][NT];
    #pragma unroll
    for (int kt = 0; kt < 4; ++kt)
        #pragma unroll
        for (int nt = 0; nt < NT; ++nt)
            Bf[kt][nt] = *(const bf8_t*)(Bp + (size_t)kt * NCOLS * 32
                                         + (size_t)(colbase + nt * 16 + ln) * 32 + q * 8);

    #pragma unroll
    for (int rt = 0; rt < 8; ++rt) {
        int rowt = row0 + rt * 16;
        if (rowt < NN) {
            int arow = rowt + ln;
            bf8_t Af[4];
            #pragma unroll
            for (int kt = 0; kt < 4; ++kt)
                Af[kt] = *(const bf8_t*)(Ab + (size_t)arow * 128 + kt * 32 + q * 8);

            f4_t acc[NT];
            #pragma unroll
            for (int nt = 0; nt < NT; ++nt) acc[nt] = (f4_t){0.f, 0.f, 0.f, 0.f};
            #pragma unroll
            for (int kt = 0; kt < 4; ++kt)
                #pragma unroll
                for (int nt = 0; nt < NT; ++nt)
                    acc[nt] = __builtin_amdgcn_mfma_f32_16x16x32_bf16(Af[kt], Bf[kt][nt], acc[nt], 0, 0, 0);

            #pragma unroll
            for (int r = 0; r < 4; ++r) {
                int row = rowt + q * 4 + r;
                if (half == 0) {     // fp8 t-half
                    if (NT == 4) {
                        unsigned v = pk4_fp8(acc[0][r], acc[1][r], acc[2][r], acc[3][r]);
                        *(unsigned*)(Tout + (size_t)row * HC + wsub * 64 + ln * 4) = v;
                    } else {
                        unsigned short v = pk2_fp8(acc[0][r], acc[1][r]);
                        *(unsigned short*)(Tout + (size_t)row * HC + wsub * 32 + ln * 2) = v;
                    }
                } else {             // bf16 r-half
                    if (NT == 4) {
                        uint2 v;
                        v.x = (unsigned)f2bf(acc[0][r]) | ((unsigned)f2bf(acc[1][r]) << 16);
                        v.y = (unsigned)f2bf(acc[2][r]) | ((unsigned)f2bf(acc[3][r]) << 16);
                        *(uint2*)(Rout + (size_t)row * HC + wsub * 64 + ln * 4) = v;
                    } else {
                        unsigned v = (unsigned)f2bf(acc[0][r]) | ((unsigned)f2bf(acc[1][r]) << 16);
                        *(unsigned*)(Rout + (size_t)row * HC + wsub * 32 + ln * 2) = v;
                    }
                }
            }
        }
    }
}

// ---------------- merged kernels ----------------
__global__ __launch_bounds__(256) void prep_k(
    const int* __restrict__ src, const int* __restrict__ dst,
    int* __restrict__ bin_cnt, int* __restrict__ binbuf,
    const float* __restrict__ x, unsigned short* __restrict__ xb,
    const float* __restrict__ Wl0, const float* __restrict__ Wr0,
    const float* __restrict__ Wl1, const float* __restrict__ Wr1,
    const float* __restrict__ bl0, const float* __restrict__ bl1,
    unsigned short* __restrict__ Bp0, unsigned short* __restrict__ Bp1,
    float* __restrict__ b0p, float* __restrict__ b1p)
{
    if (blockIdx.x < NB1)
        binpass1_body(blockIdx.x, src, dst, bin_cnt, binbuf);
    else if (blockIdx.x < NB1 + 25)
        pack_body(blockIdx.x - NB1, Wl0, Wr0, Wl1, Wr1, bl0, bl1, Bp0, Bp1, b0p, b1p);
    else
        conv_body(blockIdx.x - NB1 - 25, x, xb);
}

__global__ __launch_bounds__(256) void gemm0_bp2_k(
    const unsigned short* __restrict__ xb, const unsigned short* __restrict__ Bp0,
    unsigned char* __restrict__ t0q, unsigned short* __restrict__ r0b,
    const int* __restrict__ binbuf, const int* __restrict__ bin_cnt,
    int* __restrict__ csr, int* __restrict__ row_ptr, float* __restrict__ invd)
{
    if (blockIdx.x < GEMMB)
        gemm_body<256>(blockIdx.x, xb, Bp0, t0q, r0b);
    else
        binpass2_body(blockIdx.x - GEMMB, binbuf, bin_cnt, csr, row_ptr, invd);
}

__global__ __launch_bounds__(256) void gemm1_k(
    const unsigned short* __restrict__ h1b, const unsigned short* __restrict__ Bp1,
    unsigned char* __restrict__ t1q, unsigned short* __restrict__ r1b)
{
    gemm_body<128>(blockIdx.x, h1b, Bp1, t1q, r1b);
}

// ---------------- fused gather-mean + combine (bf16 out) ----------------
__device__ __forceinline__ void unp8(float* a, uint4 v) {
    a[0] = bfl(v.x); a[1] = bfh(v.x);
    a[2] = bfl(v.y); a[3] = bfh(v.y);
    a[4] = bfl(v.z); a[5] = bfh(v.z);
    a[6] = bfl(v.w); a[7] = bfh(v.w);
}

template<int LPNS, bool RELU>
__global__ __launch_bounds__(256) void gather_fuse_k(
    const unsigned char* __restrict__ tq, const int* __restrict__ csr,
    const int* __restrict__ row_ptr, const float* __restrict__ invd,
    const unsigned short* __restrict__ rg, const float* __restrict__ biasp,
    unsigned short* __restrict__ hout)
{
    constexpr int STRIDE = 8 << LPNS;   // fp8 row bytes == bf16 row elements
    int t = blockIdx.x * 256 + threadIdx.x;
    int node = t >> LPNS;
    int lane = t & ((1 << LPNS) - 1);
    if (node >= NN) return;
    int e = row_ptr[node];
    int e1 = row_ptr[node + 1];
    const unsigned char* fb = tq + lane * 8;

    float a0[8] = {0.f, 0.f, 0.f, 0.f, 0.f, 0.f, 0.f, 0.f};
    float a1[8] = {0.f, 0.f, 0.f, 0.f, 0.f, 0.f, 0.f, 0.f};
    for (; e + 3 < e1; e += 4) {
        int s0 = csr[e], s1 = csr[e + 1], s2 = csr[e + 2], s3 = csr[e + 3];
        uint2 v0 = *(const uint2*)(fb + (size_t)s0 * STRIDE);
        uint2 v1 = *(const uint2*)(fb + (size_t)s1 * STRIDE);
        uint2 v2 = *(const uint2*)(fb + (size_t)s2 * STRIDE);
        uint2 v3 = *(const uint2*)(fb + (size_t)s3 * STRIDE);
        accf8(a0, v0); accf8(a1, v1); accf8(a0, v2); accf8(a1, v3);
    }
    for (; e < e1; ++e) {
        int s0 = csr[e];
        uint2 v0 = *(const uint2*)(fb + (size_t)s0 * STRIDE);
        accf8(a0, v0);
    }

    float inv = invd[node];
    uint4 rv = *(const uint4*)(rg + (size_t)node * STRIDE + lane * 8);
    float rr[8];
    unp8(rr, rv);
    f4_t b0 = *(const f4_t*)(biasp + lane * 8);
    f4_t b1 = *(const f4_t*)(biasp + lane * 8 + 4);
    float o[8];
    #pragma unroll
    for (int j = 0; j < 8; ++j) {
        float bj = (j < 4) ? b0[j] : b1[j - 4];
        float v = (a0[j] + a1[j]) * inv + rr[j] + bj;
        o[j] = RELU ? fmaxf(v, 0.f) : v;
    }
    uint4 w;
    w.x = (unsigned)f2bf(o[0]) | ((unsigned)f2bf(o[1]) << 16);
    w.y = (unsigned)f2bf(o[2]) | ((unsigned)f2bf(o[3]) << 16);
    w.z = (unsigned)f2bf(o[4]) | ((unsigned)f2bf(o[5]) << 16);
    w.w = (unsigned)f2bf(o[6]) | ((unsigned)f2bf(o[7]) << 16);
    *(uint4*)(hout + (size_t)node * STRIDE + lane * 8) = w;
}

// ---------------- edge scoring: 8 lanes x 8 bf16, 2 edges per group ----------------
__device__ __forceinline__ float dot8(uint4 va, uint4 vb) {
    return bfl(va.x) * bfl(vb.x) + bfh(va.x) * bfh(vb.x)
         + bfl(va.y) * bfl(vb.y) + bfh(va.y) * bfh(vb.y)
         + bfl(va.z) * bfl(vb.z) + bfh(va.z) * bfh(vb.z)
         + bfl(va.w) * bfl(vb.w) + bfh(va.w) * bfh(vb.w);
}

__global__ __launch_bounds__(256) void score_k(
    const unsigned short* __restrict__ h2b, const int* __restrict__ pos,
    const int* __restrict__ neg, float* __restrict__ out)
{
    int t = blockIdx.x * 256 + threadIdx.x;
    int g = t >> 3, l = t & 7;
    int eg0 = g * 2;
    if (eg0 >= 2 * EPE) return;
    int eg1 = eg0 + 1;
    int a0i, b0i, a1i, b1i;
    if (eg0 < EPE) { a0i = pos[eg0]; b0i = pos[EPE + eg0]; }
    else { int e2 = eg0 - EPE; a0i = neg[e2]; b0i = neg[EPE + e2]; }
    if (eg1 < EPE) { a1i = pos[eg1]; b1i = pos[EPE + eg1]; }
    else { int e2 = eg1 - EPE; a1i = neg[e2]; b1i = neg[EPE + e2]; }
    const unsigned short* hb = h2b + (size_t)l * 8;
    uint4 va0 = *(const uint4*)(hb + (size_t)a0i * 64);
    uint4 vb0 = *(const uint4*)(hb + (size_t)b0i * 64);
    uint4 va1 = *(const uint4*)(hb + (size_t)a1i * 64);
    uint4 vb1 = *(const uint4*)(hb + (size_t)b1i * 64);
    float p0 = dot8(va0, vb0);
    float p1 = dot8(va1, vb1);
    p0 += __shfl_xor(p0, 1, 8);
    p1 += __shfl_xor(p1, 1, 8);
    p0 += __shfl_xor(p0, 2, 8);
    p1 += __shfl_xor(p1, 2, 8);
    p0 += __shfl_xor(p0, 4, 8);
    p1 += __shfl_xor(p1, 4, 8);
    if (l == 0) { out[eg0] = p0; out[eg1] = p1; }
}

extern "C" void kernel_launch(void* const* d_in, const int* in_sizes, int n_in,
                              void* d_out, int out_size, void* d_ws, size_t ws_size,
                              hipStream_t stream) {
    const float* x   = (const float*)d_in[0];
    const int*   ei  = (const int*)d_in[1];
    const int*   pei = (const int*)d_in[2];
    const int*   nei = (const int*)d_in[3];
    const float* Wl0 = (const float*)d_in[4];
    const float* bl0 = (const float*)d_in[5];
    const float* Wr0 = (const float*)d_in[6];
    const float* Wl1 = (const float*)d_in[7];
    const float* bl1 = (const float*)d_in[8];
    const float* Wr1 = (const float*)d_in[9];
    float* out = (float*)d_out;

    char* ws = (char*)d_ws;
    size_t off = 0;
    auto alloc = [&](size_t bytes) {
        void* p = ws + off;
        off = (off + bytes + 255) & ~(size_t)255;
        return p;
    };
    float* invd     = (float*)alloc((size_t)NN * 4);
    int*   row_ptr  = (int*)  alloc((size_t)(NN + 1) * 4);
    int*   bin_cnt  = (int*)  alloc((size_t)NBINS * 4);
    int*   binbuf   = (int*)  alloc((size_t)NBINS * BCAP * 4);
    int*   csr      = (int*)  alloc((size_t)EE * 4);
    unsigned short* Bp0 = (unsigned short*)alloc((size_t)4096 * 8 * 2);
    unsigned short* Bp1 = (unsigned short*)alloc((size_t)2048 * 8 * 2);
    float* b0p = (float*)alloc(128 * 4);
    float* b1p = (float*)alloc(64 * 4);
    unsigned short* xb  = (unsigned short*)alloc((size_t)NN * 128 * 2);  // x in bf16
    unsigned char*  t0q = (unsigned char*) alloc((size_t)NN * 128);      // fp8; t1q aliases
    unsigned short* r0b = (unsigned short*)alloc((size_t)NN * 128 * 2);  // r1b aliases
    unsigned short* h1b = (unsigned short*)alloc((size_t)NN * 128 * 2);  // h2b aliases
    unsigned char*  t1q = t0q;
    unsigned short* r1b = r0b;
    unsigned short* h2b = h1b;   // h1b dead once gemm1 done

    const int* src = ei;        // edge_index[0]
    const int* dst = ei + EE;   // edge_index[1]

    hipMemsetAsync(bin_cnt, 0, (size_t)NBINS * 4, stream);

    // K1: binpass1 || pack || x->bf16 convert (mutually independent)
    prep_k<<<NB1 + 25 + CONVB, 256, 0, stream>>>(
        src, dst, bin_cnt, binbuf, x, xb,
        Wl0, Wr0, Wl1, Wr1, bl0, bl1, Bp0, Bp1, b0p, b1p);

    // K2: gemm0 || binpass2 (independent)
    gemm0_bp2_k<<<GEMMB + NBINS, 256, 0, stream>>>(
        xb, Bp0, t0q, r0b, binbuf, bin_cnt, csr, row_ptr, invd);

    // K3: h1 = relu(mean(t0) + r0 + b0)   (bf16 out)
    gather_fuse_k<4, true><<<(NN * 16 + 255) / 256, 256, 0, stream>>>(
        t0q, csr, row_ptr, invd, r0b, b0p, h1b);

    // K4: [t1 | r1] = h1 @ [Wl1 | Wr1]
    gemm1_k<<<GEMMB, 256, 0, stream>>>(h1b, Bp1, t1q, r1b);

    // K5: h2 = mean(t1) + r1 + b1   (bf16 out — fp8 h2 fails accuracy)
    gather_fuse_k<3, false><<<(NN * 8 + 255) / 256, 256, 0, stream>>>(
        t1q, csr, row_ptr, invd, r1b, b1p, h2b);

    // K6: scoring (2 edges per 8-lane group)
    score_k<<<(EPE * 8 + 255) / 256, 256, 0, stream>>>(h2b, pei, nei, out);
}

// Round 11
// 280.885 us; speedup vs baseline: 1.7212x; 1.0120x over previous
//
#include <hip/hip_runtime.h>

#define NN 100000
#define EE 1600000
#define EPE 500000
#define NBINS 196        // ceil(NN/512), bin = dst >> 9
#define BCAP 12288       // slots per bin
#define EPB 4096         // edges per block in binpass1
#define NB1 391          // ceil(EE/EPB)
#define GEMMB 782        // gemm blocks: ceil(NN/128)
#define CONVB 1563       // x->bf16 blocks: ceil(NN*128/(256*32))

typedef short bf8_t __attribute__((ext_vector_type(8)));   // 8 x bf16 (4 VGPRs)
typedef float f4_t  __attribute__((ext_vector_type(4)));   // MFMA accumulator
typedef float f2v  __attribute__((ext_vector_type(2)));

__device__ __forceinline__ unsigned short f2bf(float f) {
    unsigned u = __float_as_uint(f);
    unsigned r = (u + 0x7fffu + ((u >> 16) & 1u)) >> 16;   // RNE
    return (unsigned short)r;
}
__device__ __forceinline__ float bfl(unsigned u) { return __uint_as_float(u << 16); }
__device__ __forceinline__ float bfh(unsigned u) { return __uint_as_float(u & 0xffff0000u); }

// storage perms (mem offset within half-row -> true col within half):
__device__ __forceinline__ int c0p(int m) {
    return ((m >> 6) & 1) * 64 + (m & 3) * 16 + ((m >> 2) & 15);
}
__device__ __forceinline__ int c1p(int m) {
    return ((m >> 5) & 1) * 32 + (m & 1) * 16 + ((m >> 1) & 15);
}

// ---------------- fp8 e4m3 (t0/t1 message tensors ONLY — h2 stays bf16,
// fp8 h2 failed accuracy in R9: absmax 0.203 > 0.16) ----------------
#if __has_builtin(__builtin_amdgcn_cvt_pk_fp8_f32) && __has_builtin(__builtin_amdgcn_cvt_pk_f32_fp8)
__device__ __forceinline__ unsigned pk4_fp8(float a0, float a1, float a2, float a3) {
    int w = 0;
    w = __builtin_amdgcn_cvt_pk_fp8_f32(a0, a1, w, false);
    w = __builtin_amdgcn_cvt_pk_fp8_f32(a2, a3, w, true);
    return (unsigned)w;
}
__device__ __forceinline__ unsigned short pk2_fp8(float a0, float a1) {
    int w = __builtin_amdgcn_cvt_pk_fp8_f32(a0, a1, 0, false);
    return (unsigned short)(w & 0xffff);
}
__device__ __forceinline__ void accf8(float* a, unsigned lo, unsigned hi) {
    f2v p0 = __builtin_amdgcn_cvt_pk_f32_fp8((int)lo, false);
    f2v p1 = __builtin_amdgcn_cvt_pk_f32_fp8((int)lo, true);
    f2v p2 = __builtin_amdgcn_cvt_pk_f32_fp8((int)hi, false);
    f2v p3 = __builtin_amdgcn_cvt_pk_f32_fp8((int)hi, true);
    a[0] += p0.x; a[1] += p0.y; a[2] += p1.x; a[3] += p1.y;
    a[4] += p2.x; a[5] += p2.y; a[6] += p3.x; a[7] += p3.y;
}
#else
#include <hip/hip_fp8.h>
__device__ __forceinline__ unsigned pk4_fp8(float a0, float a1, float a2, float a3) {
    unsigned r;
    r  = (unsigned)__hip_cvt_float_to_fp8(a0, __HIP_SATFINITE, __HIP_E4M3);
    r |= (unsigned)__hip_cvt_float_to_fp8(a1, __HIP_SATFINITE, __HIP_E4M3) << 8;
    r |= (unsigned)__hip_cvt_float_to_fp8(a2, __HIP_SATFINITE, __HIP_E4M3) << 16;
    r |= (unsigned)__hip_cvt_float_to_fp8(a3, __HIP_SATFINITE, __HIP_E4M3) << 24;
    return r;
}
__device__ __forceinline__ unsigned short pk2_fp8(float a0, float a1) {
    unsigned r;
    r  = (unsigned)__hip_cvt_float_to_fp8(a0, __HIP_SATFINITE, __HIP_E4M3);
    r |= (unsigned)__hip_cvt_float_to_fp8(a1, __HIP_SATFINITE, __HIP_E4M3) << 8;
    return (unsigned short)r;
}
__device__ __forceinline__ float dec1_fp8(unsigned b) {
    __hip_fp8_e4m3 h; h.__x = (__hip_fp8_storage_t)(b & 0xff);
    return (float)h;
}
__device__ __forceinline__ void accf8(float* a, unsigned lo, unsigned hi) {
    a[0] += dec1_fp8(lo); a[1] += dec1_fp8(lo >> 8);
    a[2] += dec1_fp8(lo >> 16); a[3] += dec1_fp8(lo >> 24);
    a[4] += dec1_fp8(hi); a[5] += dec1_fp8(hi >> 8);
    a[6] += dec1_fp8(hi >> 16); a[7] += dec1_fp8(hi >> 24);
}
#endif

// ---------------- phase bodies ----------------
__device__ void binpass1_body(int blk, const int* __restrict__ src,
                              const int* __restrict__ dst,
                              int* __restrict__ bin_cnt, int* __restrict__ binbuf)
{
    __shared__ int cnt_l[NBINS];
    __shared__ int base_l[NBINS];
    int tid = threadIdx.x;
    int e0 = blk * EPB;
    for (int i = tid; i < NBINS; i += 256) cnt_l[i] = 0;
    __syncthreads();

    int pk[16];
    #pragma unroll
    for (int i = 0; i < 16; ++i) {
        int e = e0 + tid + i * 256;
        pk[i] = -1;
        if (e < EE) {
            int d = dst[e];
            int b = d >> 9;
            int r = atomicAdd(&cnt_l[b], 1);        // r < 4096
            pk[i] = (b << 21) | ((d & 511) << 12) | r;
        }
    }
    __syncthreads();
    for (int i = tid; i < NBINS; i += 256)
        base_l[i] = atomicAdd(&bin_cnt[i], cnt_l[i]);
    __syncthreads();

    #pragma unroll
    for (int i = 0; i < 16; ++i) {
        int e = e0 + tid + i * 256;
        if (e >= EE) continue;
        int v = pk[i];
        int b = v >> 21, dl = (v >> 12) & 511, r = v & 4095;
        binbuf[b * BCAP + base_l[b] + r] = (dl << 17) | src[e];  // src<2^17
    }
}

__device__ void binpass2_body(int b, const int* __restrict__ binbuf,
                              const int* __restrict__ bin_cnt, int* __restrict__ csr,
                              int* __restrict__ row_ptr, float* __restrict__ invd)
{
    __shared__ int deg_l[512];
    __shared__ int off_l[512];
    __shared__ int cur_l[512];
    __shared__ int s[256];
    int tid = threadIdx.x;
    int lo = b << 9;
    int n_here = min(512, NN - lo);

    int bc = (tid < NBINS) ? bin_cnt[tid] : 0;
    s[tid] = bc;
    __syncthreads();
    #pragma unroll
    for (int off = 1; off < 256; off <<= 1) {
        int t = (tid >= off) ? s[tid - off] : 0;
        __syncthreads();
        s[tid] += t;
        __syncthreads();
    }
    int base = (b == 0) ? 0 : s[b - 1];
    int cnt = bin_cnt[b];
    const int* bb = binbuf + b * BCAP;
    __syncthreads();

    deg_l[tid] = 0; deg_l[tid + 256] = 0;
    __syncthreads();
    for (int i = tid; i < cnt; i += 256)
        atomicAdd(&deg_l[bb[i] >> 17], 1);
    __syncthreads();

    int a0 = deg_l[2 * tid], a1 = deg_l[2 * tid + 1];
    s[tid] = a0 + a1;
    __syncthreads();
    #pragma unroll
    for (int off = 1; off < 256; off <<= 1) {
        int t = (tid >= off) ? s[tid - off] : 0;
        __syncthreads();
        s[tid] += t;
        __syncthreads();
    }
    int excl = s[tid] - (a0 + a1);
    off_l[2 * tid] = excl;
    off_l[2 * tid + 1] = excl + a0;
    cur_l[2 * tid] = excl;
    cur_l[2 * tid + 1] = excl + a0;
    __syncthreads();

    for (int j = tid; j < n_here; j += 256) {
        row_ptr[lo + j] = base + off_l[j];
        invd[lo + j] = 1.0f / fmaxf((float)deg_l[j], 1.0f);
    }
    if (tid == 0 && b == NBINS - 1) row_ptr[NN] = EE;

    for (int i = tid; i < cnt; i += 256) {
        int v = bb[i];
        int dstl = v >> 17, srcv = v & 0x1FFFF;
        int pos = atomicAdd(&cur_l[dstl], 1);
        csr[base + pos] = srcv;
    }
}

__device__ void pack_body(int blk, const float* __restrict__ Wl0, const float* __restrict__ Wr0,
                          const float* __restrict__ Wl1, const float* __restrict__ Wr1,
                          const float* __restrict__ bl0, const float* __restrict__ bl1,
                          unsigned short* __restrict__ Bp0, unsigned short* __restrict__ Bp1,
                          float* __restrict__ b0p, float* __restrict__ b1p)
{
    int t = blk * 256 + threadIdx.x;
    if (t < 4096) {                     // Bp0: (kt, n, q), ntot=256, ncl=128
        int q = t & 3;
        int n = (t >> 2) & 255;
        int kt = t >> 10;
        unsigned short o[8];
        #pragma unroll
        for (int j = 0; j < 8; ++j) {
            int k = kt * 32 + q * 8 + j;
            float v = (n < 128) ? Wl0[(size_t)k * 128 + n] : Wr0[(size_t)k * 128 + (n - 128)];
            o[j] = f2bf(v);
        }
        uint4 w;
        w.x = (unsigned)o[0] | ((unsigned)o[1] << 16);
        w.y = (unsigned)o[2] | ((unsigned)o[3] << 16);
        w.z = (unsigned)o[4] | ((unsigned)o[5] << 16);
        w.w = (unsigned)o[6] | ((unsigned)o[7] << 16);
        *(uint4*)(Bp0 + (size_t)t * 8) = w;
    } else if (t < 6144) {              // Bp1: ntot=128, ncl=64, h1-perm rows
        int u = t - 4096;
        int q = u & 3;
        int n = (u >> 2) & 127;
        int kt = u >> 9;
        unsigned short o[8];
        #pragma unroll
        for (int j = 0; j < 8; ++j) {
            int k = kt * 32 + q * 8 + j;          // h1 mem offset
            int c = c0p(k);                       // true column
            float v = (n < 64) ? Wl1[(size_t)c * 64 + n] : Wr1[(size_t)c * 64 + (n - 64)];
            o[j] = f2bf(v);
        }
        uint4 w;
        w.x = (unsigned)o[0] | ((unsigned)o[1] << 16);
        w.y = (unsigned)o[2] | ((unsigned)o[3] << 16);
        w.z = (unsigned)o[4] | ((unsigned)o[5] << 16);
        w.w = (unsigned)o[6] | ((unsigned)o[7] << 16);
        *(uint4*)(Bp1 + (size_t)u * 8) = w;
    } else if (t < 6144 + 128) {
        int m = t - 6144;
        b0p[m] = bl0[c0p(m)];
    } else if (t < 6144 + 192) {
        int m = t - 6272;
        b1p[m] = bl1[c1p(m)];
    }
}

// 32 floats per thread: 8 independent float4 loads in flight, 4 uint4 stores.
__device__ void conv_body(int blk, const float* __restrict__ x, unsigned short* __restrict__ xb)
{
    int i = blk * 256 + threadIdx.x;
    if (i >= (NN * 128) / 32) return;
    const float4* xp = (const float4*)x + (size_t)i * 8;
    float4 v[8];
    #pragma unroll
    for (int j = 0; j < 8; ++j) v[j] = xp[j];
    uint4* op = (uint4*)(xb + (size_t)i * 32);
    #pragma unroll
    for (int j = 0; j < 4; ++j) {
        float4 a = v[2 * j], b = v[2 * j + 1];
        uint4 w;
        w.x = (unsigned)f2bf(a.x) | ((unsigned)f2bf(a.y) << 16);
        w.y = (unsigned)f2bf(a.z) | ((unsigned)f2bf(a.w) << 16);
        w.z = (unsigned)f2bf(b.x) | ((unsigned)f2bf(b.y) << 16);
        w.w = (unsigned)f2bf(b.z) | ((unsigned)f2bf(b.w) << 16);
        op[j] = w;
    }
}

// ---------------- MFMA GEMM body: [t | r] = A @ [Wl | Wr], K=128, 128 rows/block ----------------
template<int NCOLS>
__device__ __forceinline__ void gemm_body(
    int blk, const unsigned short* __restrict__ Ab, const unsigned short* __restrict__ Bp,
    unsigned char* __restrict__ Tout, unsigned short* __restrict__ Rout)
{
    constexpr int STRIP = NCOLS / 4;
    constexpr int NT = STRIP / 16;    // 4 (layer0) or 2 (layer1)
    constexpr int HC = NCOLS / 2;
    int w = threadIdx.x >> 6;
    int lane = threadIdx.x & 63;
    int ln = lane & 15, q = lane >> 4;
    int half = w >> 1, wsub = w & 1;
    int row0 = blk * 128;
    int colbase = half * HC + wsub * STRIP;

    bf8_t Bf[4][NT];
    #pragma unroll
    for (int kt = 0; kt < 4; ++kt)
        #pragma unroll
        for (int nt = 0; nt < NT; ++nt)
            Bf[kt][nt] = *(const bf8_t*)(Bp + (size_t)kt * NCOLS * 32
                                         + (size_t)(colbase + nt * 16 + ln) * 32 + q * 8);

    #pragma unroll
    for (int rt = 0; rt < 8; ++rt) {
        int rowt = row0 + rt * 16;
        if (rowt < NN) {
            int arow = rowt + ln;
            bf8_t Af[4];
            #pragma unroll
            for (int kt = 0; kt < 4; ++kt)
                Af[kt] = *(const bf8_t*)(Ab + (size_t)arow * 128 + kt * 32 + q * 8);

            f4_t acc[NT];
            #pragma unroll
            for (int nt = 0; nt < NT; ++nt) acc[nt] = (f4_t){0.f, 0.f, 0.f, 0.f};
            #pragma unroll
            for (int kt = 0; kt < 4; ++kt)
                #pragma unroll
                for (int nt = 0; nt < NT; ++nt)
                    acc[nt] = __builtin_amdgcn_mfma_f32_16x16x32_bf16(Af[kt], Bf[kt][nt], acc[nt], 0, 0, 0);

            #pragma unroll
            for (int r = 0; r < 4; ++r) {
                int row = rowt + q * 4 + r;
                if (half == 0) {     // fp8 t-half
                    if (NT == 4) {
                        unsigned v = pk4_fp8(acc[0][r], acc[1][r], acc[2][r], acc[3][r]);
                        *(unsigned*)(Tout + (size_t)row * HC + wsub * 64 + ln * 4) = v;
                    } else {
                        unsigned short v = pk2_fp8(acc[0][r], acc[1][r]);
                        *(unsigned short*)(Tout + (size_t)row * HC + wsub * 32 + ln * 2) = v;
                    }
                } else {             // bf16 r-half
                    if (NT == 4) {
                        uint2 v;
                        v.x = (unsigned)f2bf(acc[0][r]) | ((unsigned)f2bf(acc[1][r]) << 16);
                        v.y = (unsigned)f2bf(acc[2][r]) | ((unsigned)f2bf(acc[3][r]) << 16);
                        *(uint2*)(Rout + (size_t)row * HC + wsub * 64 + ln * 4) = v;
                    } else {
                        unsigned v = (unsigned)f2bf(acc[0][r]) | ((unsigned)f2bf(acc[1][r]) << 16);
                        *(unsigned*)(Rout + (size_t)row * HC + wsub * 32 + ln * 2) = v;
                    }
                }
            }
        }
    }
}

// ---------------- merged kernels ----------------
__global__ __launch_bounds__(256) void prep_k(
    const int* __restrict__ src, const int* __restrict__ dst,
    int* __restrict__ bin_cnt, int* __restrict__ binbuf,
    const float* __restrict__ x, unsigned short* __restrict__ xb,
    const float* __restrict__ Wl0, const float* __restrict__ Wr0,
    const float* __restrict__ Wl1, const float* __restrict__ Wr1,
    const float* __restrict__ bl0, const float* __restrict__ bl1,
    unsigned short* __restrict__ Bp0, unsigned short* __restrict__ Bp1,
    float* __restrict__ b0p, float* __restrict__ b1p)
{
    if (blockIdx.x < NB1)
        binpass1_body(blockIdx.x, src, dst, bin_cnt, binbuf);
    else if (blockIdx.x < NB1 + 25)
        pack_body(blockIdx.x - NB1, Wl0, Wr0, Wl1, Wr1, bl0, bl1, Bp0, Bp1, b0p, b1p);
    else
        conv_body(blockIdx.x - NB1 - 25, x, xb);
}

__global__ __launch_bounds__(256) void gemm0_bp2_k(
    const unsigned short* __restrict__ xb, const unsigned short* __restrict__ Bp0,
    unsigned char* __restrict__ t0q, unsigned short* __restrict__ r0b,
    const int* __restrict__ binbuf, const int* __restrict__ bin_cnt,
    int* __restrict__ csr, int* __restrict__ row_ptr, float* __restrict__ invd)
{
    if (blockIdx.x < GEMMB)
        gemm_body<256>(blockIdx.x, xb, Bp0, t0q, r0b);
    else
        binpass2_body(blockIdx.x - GEMMB, binbuf, bin_cnt, csr, row_ptr, invd);
}

__global__ __launch_bounds__(256) void gemm1_k(
    const unsigned short* __restrict__ h1b, const unsigned short* __restrict__ Bp1,
    unsigned char* __restrict__ t1q, unsigned short* __restrict__ r1b)
{
    gemm_body<128>(blockIdx.x, h1b, Bp1, t1q, r1b);
}

// ---------------- fused gather-mean + combine (bf16 out) ----------------
// 1<<LPNS2 lanes per node, 16 cols (16 B fp8 / 32 B bf16) per lane.
__device__ __forceinline__ void unp8(float* a, uint4 v) {
    a[0] = bfl(v.x); a[1] = bfh(v.x);
    a[2] = bfl(v.y); a[3] = bfh(v.y);
    a[4] = bfl(v.z); a[5] = bfh(v.z);
    a[6] = bfl(v.w); a[7] = bfh(v.w);
}

template<int LPNS2, bool RELU>
__global__ __launch_bounds__(256) void gather_fuse_k(
    const unsigned char* __restrict__ tq, const int* __restrict__ csr,
    const int* __restrict__ row_ptr, const float* __restrict__ invd,
    const unsigned short* __restrict__ rg, const float* __restrict__ biasp,
    unsigned short* __restrict__ hout)
{
    constexpr int ROW = 16 << LPNS2;    // cols per row (=fp8 bytes per row)
    int t = blockIdx.x * 256 + threadIdx.x;
    int node = t >> LPNS2;
    int lane = t & ((1 << LPNS2) - 1);
    if (node >= NN) return;
    int e = row_ptr[node];
    int e1 = row_ptr[node + 1];
    const unsigned char* fb = tq + lane * 16;

    float a0[16], a1[16];
    #pragma unroll
    for (int j = 0; j < 16; ++j) { a0[j] = 0.f; a1[j] = 0.f; }

    for (; e + 3 < e1; e += 4) {
        int s0 = csr[e], s1 = csr[e + 1], s2 = csr[e + 2], s3 = csr[e + 3];
        uint4 v0 = *(const uint4*)(fb + (size_t)s0 * ROW);
        uint4 v1 = *(const uint4*)(fb + (size_t)s1 * ROW);
        uint4 v2 = *(const uint4*)(fb + (size_t)s2 * ROW);
        uint4 v3 = *(const uint4*)(fb + (size_t)s3 * ROW);
        accf8(a0, v0.x, v0.y); accf8(a0 + 8, v0.z, v0.w);
        accf8(a1, v1.x, v1.y); accf8(a1 + 8, v1.z, v1.w);
        accf8(a0, v2.x, v2.y); accf8(a0 + 8, v2.z, v2.w);
        accf8(a1, v3.x, v3.y); accf8(a1 + 8, v3.z, v3.w);
    }
    for (; e < e1; ++e) {
        int s0 = csr[e];
        uint4 v0 = *(const uint4*)(fb + (size_t)s0 * ROW);
        accf8(a0, v0.x, v0.y); accf8(a0 + 8, v0.z, v0.w);
    }

    float inv = invd[node];
    const unsigned short* rp = rg + (size_t)node * ROW + lane * 16;
    uint4 rv0 = *(const uint4*)rp;
    uint4 rv1 = *(const uint4*)(rp + 8);
    float rr[16];
    unp8(rr, rv0); unp8(rr + 8, rv1);
    const float* bp = biasp + lane * 16;

    float o[16];
    #pragma unroll
    for (int j = 0; j < 16; ++j) {
        float v = (a0[j] + a1[j]) * inv + rr[j] + bp[j];
        o[j] = RELU ? fmaxf(v, 0.f) : v;
    }
    uint4 w0, w1;
    w0.x = (unsigned)f2bf(o[0])  | ((unsigned)f2bf(o[1])  << 16);
    w0.y = (unsigned)f2bf(o[2])  | ((unsigned)f2bf(o[3])  << 16);
    w0.z = (unsigned)f2bf(o[4])  | ((unsigned)f2bf(o[5])  << 16);
    w0.w = (unsigned)f2bf(o[6])  | ((unsigned)f2bf(o[7])  << 16);
    w1.x = (unsigned)f2bf(o[8])  | ((unsigned)f2bf(o[9])  << 16);
    w1.y = (unsigned)f2bf(o[10]) | ((unsigned)f2bf(o[11]) << 16);
    w1.z = (unsigned)f2bf(o[12]) | ((unsigned)f2bf(o[13]) << 16);
    w1.w = (unsigned)f2bf(o[14]) | ((unsigned)f2bf(o[15]) << 16);
    unsigned short* op = hout + (size_t)node * ROW + lane * 16;
    *(uint4*)op = w0;
    *(uint4*)(op + 8) = w1;
}

// ---------------- edge scoring: 8 lanes x 8 bf16, 2 edges per group ----------------
__device__ __forceinline__ float dot8(uint4 va, uint4 vb) {
    return bfl(va.x) * bfl(vb.x) + bfh(va.x) * bfh(vb.x)
         + bfl(va.y) * bfl(vb.y) + bfh(va.y) * bfh(vb.y)
         + bfl(va.z) * bfl(vb.z) + bfh(va.z) * bfh(vb.z)
         + bfl(va.w) * bfl(vb.w) + bfh(va.w) * bfh(vb.w);
}

__global__ __launch_bounds__(256) void score_k(
    const unsigned short* __restrict__ h2b, const int* __restrict__ pos,
    const int* __restrict__ neg, float* __restrict__ out)
{
    int t = blockIdx.x * 256 + threadIdx.x;
    int g = t >> 3, l = t & 7;
    int eg0 = g * 2;
    if (eg0 >= 2 * EPE) return;
    int eg1 = eg0 + 1;
    int a0i, b0i, a1i, b1i;
    if (eg0 < EPE) { a0i = pos[eg0]; b0i = pos[EPE + eg0]; }
    else { int e2 = eg0 - EPE; a0i = neg[e2]; b0i = neg[EPE + e2]; }
    if (eg1 < EPE) { a1i = pos[eg1]; b1i = pos[EPE + eg1]; }
    else { int e2 = eg1 - EPE; a1i = neg[e2]; b1i = neg[EPE + e2]; }
    const unsigned short* hb = h2b + (size_t)l * 8;
    uint4 va0 = *(const uint4*)(hb + (size_t)a0i * 64);
    uint4 vb0 = *(const uint4*)(hb + (size_t)b0i * 64);
    uint4 va1 = *(const uint4*)(hb + (size_t)a1i * 64);
    uint4 vb1 = *(const uint4*)(hb + (size_t)b1i * 64);
    float p0 = dot8(va0, vb0);
    float p1 = dot8(va1, vb1);
    p0 += __shfl_xor(p0, 1, 8);
    p1 += __shfl_xor(p1, 1, 8);
    p0 += __shfl_xor(p0, 2, 8);
    p1 += __shfl_xor(p1, 2, 8);
    p0 += __shfl_xor(p0, 4, 8);
    p1 += __shfl_xor(p1, 4, 8);
    if (l == 0) { out[eg0] = p0; out[eg1] = p1; }
}

extern "C" void kernel_launch(void* const* d_in, const int* in_sizes, int n_in,
                              void* d_out, int out_size, void* d_ws, size_t ws_size,
                              hipStream_t stream) {
    const float* x   = (const float*)d_in[0];
    const int*   ei  = (const int*)d_in[1];
    const int*   pei = (const int*)d_in[2];
    const int*   nei = (const int*)d_in[3];
    const float* Wl0 = (const float*)d_in[4];
    const float* bl0 = (const float*)d_in[5];
    const float* Wr0 = (const float*)d_in[6];
    const float* Wl1 = (const float*)d_in[7];
    const float* bl1 = (const float*)d_in[8];
    const float* Wr1 = (const float*)d_in[9];
    float* out = (float*)d_out;

    char* ws = (char*)d_ws;
    size_t off = 0;
    auto alloc = [&](size_t bytes) {
        void* p = ws + off;
        off = (off + bytes + 255) & ~(size_t)255;
        return p;
    };
    float* invd     = (float*)alloc((size_t)NN * 4);
    int*   row_ptr  = (int*)  alloc((size_t)(NN + 1) * 4);
    int*   bin_cnt  = (int*)  alloc((size_t)NBINS * 4);
    int*   binbuf   = (int*)  alloc((size_t)NBINS * BCAP * 4);
    int*   csr      = (int*)  alloc((size_t)EE * 4);
    unsigned short* Bp0 = (unsigned short*)alloc((size_t)4096 * 8 * 2);
    unsigned short* Bp1 = (unsigned short*)alloc((size_t)2048 * 8 * 2);
    float* b0p = (float*)alloc(128 * 4);
    float* b1p = (float*)alloc(64 * 4);
    unsigned short* xb  = (unsigned short*)alloc((size_t)NN * 128 * 2);  // x in bf16
    unsigned char*  t0q = (unsigned char*) alloc((size_t)NN * 128);      // fp8; t1q aliases
    unsigned short* r0b = (unsigned short*)alloc((size_t)NN * 128 * 2);  // r1b aliases
    unsigned short* h1b = (unsigned short*)alloc((size_t)NN * 128 * 2);  // h2b aliases
    unsigned char*  t1q = t0q;
    unsigned short* r1b = r0b;
    unsigned short* h2b = h1b;   // h1b dead once gemm1 done

    const int* src = ei;        // edge_index[0]
    const int* dst = ei + EE;   // edge_index[1]

    hipMemsetAsync(bin_cnt, 0, (size_t)NBINS * 4, stream);

    // K1: binpass1 || pack || x->bf16 convert (mutually independent)
    prep_k<<<NB1 + 25 + CONVB, 256, 0, stream>>>(
        src, dst, bin_cnt, binbuf, x, xb,
        Wl0, Wr0, Wl1, Wr1, bl0, bl1, Bp0, Bp1, b0p, b1p);

    // K2: gemm0 || binpass2 (independent)
    gemm0_bp2_k<<<GEMMB + NBINS, 256, 0, stream>>>(
        xb, Bp0, t0q, r0b, binbuf, bin_cnt, csr, row_ptr, invd);

    // K3: h1 = relu(mean(t0) + r0 + b0)   (bf16 out, 8 lanes/node x 16B)
    gather_fuse_k<3, true><<<(NN * 8 + 255) / 256, 256, 0, stream>>>(
        t0q, csr, row_ptr, invd, r0b, b0p, h1b);

    // K4: [t1 | r1] = h1 @ [Wl1 | Wr1]
    gemm1_k<<<GEMMB, 256, 0, stream>>>(h1b, Bp1, t1q, r1b);

    // K5: h2 = mean(t1) + r1 + b1   (bf16 out, 4 lanes/node x 16B)
    gather_fuse_k<2, false><<<(NN * 4 + 255) / 256, 256, 0, stream>>>(
        t1q, csr, row_ptr, invd, r1b, b1p, h2b);

    // K6: scoring (2 edges per 8-lane group)
    score_k<<<(EPE * 8 + 255) / 256, 256, 0, stream>>>(h2b, pei, nei, out);
}